// Round 1
// baseline (593.128 us; speedup 1.0000x reference)
//
#include <hip/hip_runtime.h>
#include <math.h>

// ---------------------------------------------------------------------------
// Intra_graph forward, MI355X. Round 1: correct f32 implementation with
// algebraic restructuring:
//   * x2 == mu (last EM iter)  -> never compute separately
//   * W_out @ (x2g @ post^T) == (W_out @ x2g) @ post^T  -> z [1024,64] tiny
//   * BN stats computed analytically from z, S=sum_m(post), G=post^T post
//   * epilogue fuses y=z@post^T + BN + relu(relu(.)+x) for BOTH outputs,
//     never materializing y / x3 / x4.  Biases b_out/b_out2 cancel in BN.
// ---------------------------------------------------------------------------

constexpr int BB  = 4;
constexpr int CH  = 1024;
constexpr int IN  = 256;
constexpr int ND  = 64;
constexpr int WH  = 4096;
constexpr int DCN = 128;
constexpr size_t TOT = (size_t)BB * CH * WH;

// workspace layout (float offsets)
constexpr size_t SZ_X1  = (size_t)BB * IN * WH;     // 4194304
constexpr size_t SZ_PST = (size_t)BB * WH * ND;     // 1048576
constexpr size_t SZ_MU  = (size_t)BB * IN * ND;     // 65536
constexpr size_t OFF_X1  = 0;
constexpr size_t OFF_PST = OFF_X1 + SZ_X1;
constexpr size_t OFF_MU  = OFF_PST + SZ_PST;
constexpr size_t OFF_SP  = OFF_MU + SZ_MU;                  // Spost  BB*ND
constexpr size_t OFF_PI  = OFF_SP + BB * ND;                // pi     BB*ND
constexpr size_t OFF_MUP = OFF_PI + BB * ND;                // 16*SZ_MU
constexpr size_t OFF_GP  = OFF_MUP + 16 * SZ_MU;            // 16*BB*ND*ND
constexpr size_t OFF_G   = OFF_GP + (size_t)16 * BB * ND * ND;
constexpr size_t OFF_XA  = OFF_G + (size_t)BB * ND * ND;    // BB*DCN*ND
constexpr size_t OFF_DV  = OFF_XA + (size_t)BB * DCN * ND;  // BB*DCN
constexpr size_t OFF_AH  = OFF_DV + BB * DCN;               // BB*ND*ND
constexpr size_t OFF_T2  = OFF_AH + (size_t)BB * ND * ND;   // SZ_MU
constexpr size_t OFF_X2G = OFF_T2 + SZ_MU;                  // SZ_MU
constexpr size_t OFF_Z1  = OFF_X2G + SZ_MU;                 // BB*CH*ND
constexpr size_t OFF_Z2  = OFF_Z1 + (size_t)BB * CH * ND;   // BB*CH*ND
constexpr size_t OFF_ABC = OFF_Z2 + (size_t)BB * CH * ND;   // 4*CH

// ---------------- x1 = W_in @ x + b_in   [b,256,4096], K=1024 --------------
// 128x128 tile, 8x8 micro (2x2 quadrants of 4), KT=16.
__global__ __launch_bounds__(256) void k_gemm_x1(
    const float* __restrict__ x, const float* __restrict__ Win,
    const float* __restrict__ bin, float* __restrict__ x1)
{
  __shared__ float As[16][132];   // [k][o-col], padded
  __shared__ float Bs[16][128];   // [k][m-col]
  const int t = threadIdx.x, tx = t & 15, ty = t >> 4;
  const int m0 = blockIdx.x * 128, o0 = blockIdx.y * 128, b = blockIdx.z;
  const float* xb = x + (size_t)b * CH * WH;
  float acc[8][8];
#pragma unroll
  for (int i = 0; i < 8; ++i)
#pragma unroll
    for (int j = 0; j < 8; ++j) acc[i][j] = 0.f;

  const int aoo = t >> 1, akq = (t & 1) * 8;
  const int bkk = t >> 4, bmq = (t & 15) * 8;

  for (int k0 = 0; k0 < CH; k0 += 16) {
    {
      const float* src = &Win[(size_t)(o0 + aoo) * CH + k0 + akq];
      float4 v0 = *(const float4*)(src);
      float4 v1 = *(const float4*)(src + 4);
      As[akq + 0][aoo] = v0.x; As[akq + 1][aoo] = v0.y;
      As[akq + 2][aoo] = v0.z; As[akq + 3][aoo] = v0.w;
      As[akq + 4][aoo] = v1.x; As[akq + 5][aoo] = v1.y;
      As[akq + 6][aoo] = v1.z; As[akq + 7][aoo] = v1.w;
    }
    {
      const float* src = &xb[(size_t)(k0 + bkk) * WH + m0 + bmq];
      *(float4*)&Bs[bkk][bmq]     = *(const float4*)(src);
      *(float4*)&Bs[bkk][bmq + 4] = *(const float4*)(src + 4);
    }
    __syncthreads();
#pragma unroll
    for (int kk = 0; kk < 16; ++kk) {
      float ar[8], br[8]; float4 v;
      v = *(const float4*)&As[kk][ty * 4];      ar[0]=v.x; ar[1]=v.y; ar[2]=v.z; ar[3]=v.w;
      v = *(const float4*)&As[kk][64 + ty * 4]; ar[4]=v.x; ar[5]=v.y; ar[6]=v.z; ar[7]=v.w;
      v = *(const float4*)&Bs[kk][tx * 4];      br[0]=v.x; br[1]=v.y; br[2]=v.z; br[3]=v.w;
      v = *(const float4*)&Bs[kk][64 + tx * 4]; br[4]=v.x; br[5]=v.y; br[6]=v.z; br[7]=v.w;
#pragma unroll
      for (int i = 0; i < 8; ++i)
#pragma unroll
        for (int j = 0; j < 8; ++j) acc[i][j] += ar[i] * br[j];
    }
    __syncthreads();
  }
#pragma unroll
  for (int ih = 0; ih < 2; ++ih)
#pragma unroll
    for (int i = 0; i < 4; ++i) {
      const int o = o0 + ih * 64 + ty * 4 + i;
      const float bv = bin[o];
      float* dst = &x1[((size_t)b * IN + o) * WH + m0];
#pragma unroll
      for (int jh = 0; jh < 2; ++jh) {
        float4 r;
        r.x = acc[ih*4+i][jh*4+0] + bv; r.y = acc[ih*4+i][jh*4+1] + bv;
        r.z = acc[ih*4+i][jh*4+2] + bv; r.w = acc[ih*4+i][jh*4+3] + bv;
        *(float4*)(dst + jh * 64 + tx * 4) = r;
      }
    }
}

// ---------------- init mu = multi_proto (bcast), pi = pi0 ------------------
__global__ void k_init(const float* __restrict__ mp, const float* __restrict__ pi0,
                       float* __restrict__ mu, float* __restrict__ piw)
{
  const int idx = blockIdx.x * 256 + threadIdx.x;   // grid 256 -> 65536 = SZ_MU
  mu[idx] = mp[idx & (IN * ND - 1)];
  if (idx < BB * ND) piw[idx] = pi0[idx & (ND - 1)];
}

// ---------------- lik[m][n] = sum_c x1[c][m]*mu[c][n]  (K=256) -------------
__global__ __launch_bounds__(256) void k_lik(
    const float* __restrict__ x1, const float* __restrict__ mu, float* __restrict__ lik)
{
  __shared__ float As[16][64];
  __shared__ float Bs[16][64];
  const int t = threadIdx.x, tx = t & 15, ty = t >> 4;
  const int m0 = blockIdx.x * 64, b = blockIdx.y;
  const int lkk = t >> 4, lq = (t & 15) * 4;
  float acc[4][4] = {};
  for (int c0 = 0; c0 < IN; c0 += 16) {
    *(float4*)&As[lkk][lq] = *(const float4*)&x1[((size_t)b * IN + c0 + lkk) * WH + m0 + lq];
    *(float4*)&Bs[lkk][lq] = *(const float4*)&mu[((size_t)b * IN + c0 + lkk) * ND + lq];
    __syncthreads();
#pragma unroll
    for (int kk = 0; kk < 16; ++kk) {
      float4 a4 = *(const float4*)&As[kk][ty*4];
      float4 b4 = *(const float4*)&Bs[kk][tx*4];
      float ar[4] = {a4.x,a4.y,a4.z,a4.w}, br[4] = {b4.x,b4.y,b4.z,b4.w};
#pragma unroll
      for (int i = 0; i < 4; ++i)
#pragma unroll
        for (int j = 0; j < 4; ++j) acc[i][j] += ar[i]*br[j];
    }
    __syncthreads();
  }
#pragma unroll
  for (int i = 0; i < 4; ++i) {
    float4 r = make_float4(acc[i][0], acc[i][1], acc[i][2], acc[i][3]);
    *(float4*)&lik[((size_t)b * WH + m0 + ty*4 + i) * ND + tx*4] = r;
  }
}

// ---------------- softmax over n per (b,m): post = exp(l-max)*pi, /sum -----
__global__ __launch_bounds__(256) void k_softmax(float* __restrict__ post,
                                                 const float* __restrict__ piw)
{
  const int t = threadIdx.x;
  const int w = blockIdx.x * 4 + (t >> 6);
  const int b = w >> 12, m = w & (WH - 1), lane = t & 63;
  const size_t off = ((size_t)b * WH + m) * ND + lane;
  float v = post[off];
  float mx = v;
#pragma unroll
  for (int o = 32; o; o >>= 1) mx = fmaxf(mx, __shfl_xor(mx, o));
  float e = __expf(v - mx) * piw[b * ND + lane];
  float s = e;
#pragma unroll
  for (int o = 32; o; o >>= 1) s += __shfl_xor(s, o);
  post[off] = e / (1e-18f + s);
}

// ---------------- Spost[b][n] = sum_m post, pi = Spost/WH ------------------
__global__ __launch_bounds__(1024) void k_spost(const float* __restrict__ post,
                                                float* __restrict__ sp, float* __restrict__ piw)
{
  __shared__ float red[16][64];
  const int t = threadIdx.x, b = blockIdx.x;
  const int n = t & 63, mg = t >> 6;
  float s = 0.f;
  for (int m = mg; m < WH; m += 16) s += post[((size_t)b * WH + m) * ND + n];
  red[mg][n] = s;
  __syncthreads();
  if (t < 64) {
    float a = 0.f;
#pragma unroll
    for (int g = 0; g < 16; ++g) a += red[g][t];
    sp[b * ND + t] = a;
    piw[b * ND + t] = a * (1.f / WH);
  }
}

// ---------------- mu partials: x1 @ post over m-range (K-split 16) ---------
__global__ __launch_bounds__(256) void k_mu_part(
    const float* __restrict__ x1, const float* __restrict__ post, float* __restrict__ mup)
{
  __shared__ float As[16][68];   // [k(m)][c], padded (transposed staging)
  __shared__ float Bs[16][64];   // [k(m)][n]
  const int t = threadIdx.x, tx = t & 15, ty = t >> 4;
  const int kc = blockIdx.x, c0 = blockIdx.y * 64, b = blockIdx.z;
  const int mbase = kc * 256;
  const int arow = t >> 2, akq = (t & 3) * 4;
  const int bkk = t >> 4, bnq = (t & 15) * 4;
  float acc[4][4] = {};
  for (int k0 = 0; k0 < 256; k0 += 16) {
    {
      float4 v = *(const float4*)&x1[((size_t)b * IN + c0 + arow) * WH + mbase + k0 + akq];
      As[akq + 0][arow] = v.x; As[akq + 1][arow] = v.y;
      As[akq + 2][arow] = v.z; As[akq + 3][arow] = v.w;
    }
    *(float4*)&Bs[bkk][bnq] =
        *(const float4*)&post[((size_t)b * WH + mbase + k0 + bkk) * ND + bnq];
    __syncthreads();
#pragma unroll
    for (int kk = 0; kk < 16; ++kk) {
      float4 a4 = *(const float4*)&As[kk][ty*4];
      float4 b4 = *(const float4*)&Bs[kk][tx*4];
      float ar[4] = {a4.x,a4.y,a4.z,a4.w}, br[4] = {b4.x,b4.y,b4.z,b4.w};
#pragma unroll
      for (int i = 0; i < 4; ++i)
#pragma unroll
        for (int j = 0; j < 4; ++j) acc[i][j] += ar[i]*br[j];
    }
    __syncthreads();
  }
#pragma unroll
  for (int i = 0; i < 4; ++i) {
    float4 r = make_float4(acc[i][0], acc[i][1], acc[i][2], acc[i][3]);
    *(float4*)&mup[(((size_t)kc * BB + b) * IN + c0 + ty*4 + i) * ND + tx*4] = r;
  }
}

// ---------------- mu = (sum partials) / (1e-18 + Spost[n]) -----------------
__global__ void k_mu_reduce(const float* __restrict__ mup, const float* __restrict__ sp,
                            float* __restrict__ mu)
{
  const int idx = blockIdx.x * 256 + threadIdx.x;   // grid 256 -> SZ_MU
  float s = 0.f;
#pragma unroll
  for (int kc = 0; kc < 16; ++kc) s += mup[(size_t)kc * SZ_MU + idx];
  const int n = idx & 63, b = idx >> 14;
  mu[idx] = s / (1e-18f + sp[b * ND + n]);
}

// ---------------- G partials: post^T post over m-range ---------------------
__global__ __launch_bounds__(256) void k_G_part(const float* __restrict__ post,
                                                float* __restrict__ gp)
{
  __shared__ float Ps[16][64];
  const int t = threadIdx.x, tx = t & 15, ty = t >> 4;
  const int kc = blockIdx.x, b = blockIdx.y;
  const int mbase = kc * 256;
  const int lkk = t >> 4, lnq = (t & 15) * 4;
  float acc[4][4] = {};
  for (int k0 = 0; k0 < 256; k0 += 16) {
    *(float4*)&Ps[lkk][lnq] =
        *(const float4*)&post[((size_t)b * WH + mbase + k0 + lkk) * ND + lnq];
    __syncthreads();
#pragma unroll
    for (int kk = 0; kk < 16; ++kk) {
      float4 a4 = *(const float4*)&Ps[kk][ty*4];
      float4 b4 = *(const float4*)&Ps[kk][tx*4];
      float ar[4] = {a4.x,a4.y,a4.z,a4.w}, br[4] = {b4.x,b4.y,b4.z,b4.w};
#pragma unroll
      for (int i = 0; i < 4; ++i)
#pragma unroll
        for (int j = 0; j < 4; ++j) acc[i][j] += ar[i]*br[j];
    }
    __syncthreads();
  }
#pragma unroll
  for (int i = 0; i < 4; ++i) {
    float4 r = make_float4(acc[i][0], acc[i][1], acc[i][2], acc[i][3]);
    *(float4*)&gp[((size_t)kc * BB + b) * (ND*ND) + (ty*4+i)*ND + tx*4] = r;
  }
}

__global__ void k_G_reduce(const float* __restrict__ gp, float* __restrict__ G)
{
  const int idx = blockIdx.x * 256 + threadIdx.x;   // grid 64 -> BB*ND*ND
  float s = 0.f;
#pragma unroll
  for (int kc = 0; kc < 16; ++kc) s += gp[(size_t)kc * (BB*ND*ND) + idx];
  G[idx] = s;
}

// ---------------- GC layer part 1: xa = W_adj@x2+b_adj, dvec-0.5 -----------
__global__ __launch_bounds__(256) void k_gc1(
    const float* __restrict__ x2, const float* __restrict__ Wa, const float* __restrict__ ba,
    const float* __restrict__ Wd, const float* __restrict__ bd,
    float* __restrict__ xa, float* __restrict__ dvm5)
{
  __shared__ float sx2[IN * ND];   // 64KB
  __shared__ float ssx[IN];
  const int t = threadIdx.x;
  const int dc0 = blockIdx.x * 16, b = blockIdx.y;
  const float* src = x2 + (size_t)b * IN * ND;
#pragma unroll
  for (int q = 0; q < 16; ++q)
    *(float4*)&sx2[q * 1024 + t * 4] = *(const float4*)&src[q * 1024 + t * 4];
  __syncthreads();
  {
    float s = 0.f;
#pragma unroll
    for (int q = 0; q < 16; ++q) {          // skewed start to dodge bank conflicts
      const int n4 = ((q + (t & 15)) & 15) * 4;
      float4 v = *(const float4*)&sx2[t * 64 + n4];
      s += v.x + v.y + v.z + v.w;
    }
    ssx[t] = s;
  }
  __syncthreads();
  if (t < 16) {
    const int dc = dc0 + t;
    float a = 0.f;
    for (int i = 0; i < IN; ++i) a += Wd[dc * IN + i] * ssx[i];
    const float xm = a * (1.f / ND) + bd[dc];
    dvm5[b * DCN + dc] = 1.f / (1.f + __expf(-xm)) - 0.5f;
  }
  const int dc = dc0 + (t >> 4), j0 = (t & 15) * 4;
  float a0=0.f, a1=0.f, a2=0.f, a3=0.f;
  for (int i = 0; i < IN; ++i) {
    const float w = Wa[dc * IN + i];
    const float4 v = *(const float4*)&sx2[i * 64 + j0];
    a0 += w * v.x; a1 += w * v.y; a2 += w * v.z; a3 += w * v.w;
  }
  const float bav = ba[dc];
  float4 r = make_float4(a0 + bav, a1 + bav, a2 + bav, a3 + bav);
  *(float4*)&xa[((size_t)b * DCN + dc) * ND + j0] = r;
}

// ---------------- GC part 2: A -> relu+I -> deg -> Ahat --------------------
__global__ __launch_bounds__(256) void k_gc2(
    const float* __restrict__ xa, const float* __restrict__ dvm5, float* __restrict__ ah)
{
  __shared__ float sxa[DCN * ND];   // 32KB
  __shared__ float sdv[DCN];
  __shared__ float su[ND];
  __shared__ float sdeg[ND];
  __shared__ float sA[ND * 65];
  const int t = threadIdx.x, b = blockIdx.x;
  const float* src = xa + (size_t)b * DCN * ND;
#pragma unroll
  for (int q = 0; q < 8; ++q)
    *(float4*)&sxa[q * 1024 + t * 4] = *(const float4*)&src[q * 1024 + t * 4];
  if (t < DCN) sdv[t] = dvm5[b * DCN + t];
  __syncthreads();
  if (t < ND) {
    float s = 0.f;
    for (int dc = 0; dc < DCN; ++dc) s += sxa[dc * ND + t];
    su[t] = s;
  }
  __syncthreads();
  const int n1 = t & 63, g = t >> 6;
  {
    const float u1 = su[n1];
    float acc[16];
#pragma unroll
    for (int j = 0; j < 16; ++j) acc[j] = 0.5f * u1 * su[g * 16 + j];
    for (int dc = 0; dc < DCN; ++dc) {
      const float v = sxa[dc * ND + n1] * sdv[dc];
      const float* row = &sxa[dc * ND + g * 16];
#pragma unroll
      for (int j = 0; j < 16; ++j) acc[j] += v * row[j];
    }
#pragma unroll
    for (int j = 0; j < 16; ++j) {
      const int n2 = g * 16 + j;
      sA[n1 * 65 + n2] = fmaxf(acc[j], 0.f) + (n1 == n2 ? 1.f : 0.f);
    }
  }
  __syncthreads();
  if (t < ND) {
    float s = 0.f;
    for (int m = 0; m < ND; ++m) s += sA[m * 65 + t];
    sdeg[t] = rsqrtf(s);
  }
  __syncthreads();
  {
    const int r = t >> 2, cq = (t & 3) * 16;
    const float dr = sdeg[r];
#pragma unroll
    for (int f = 0; f < 4; ++f) {
      const int c = cq + f * 4;
      float4 o;
      o.x = dr * sA[r * 65 + c + 0] * sdeg[c + 0];
      o.y = dr * sA[r * 65 + c + 1] * sdeg[c + 1];
      o.z = dr * sA[r * 65 + c + 2] * sdeg[c + 2];
      o.w = dr * sA[r * 65 + c + 3] * sdeg[c + 3];
      *(float4*)&ah[((size_t)b * ND + r) * ND + c] = o;
    }
  }
}

// ---------------- GC part 3: t2 = x2 @ Ahat --------------------------------
__global__ __launch_bounds__(256) void k_gc3(
    const float* __restrict__ x2, const float* __restrict__ ah, float* __restrict__ t2)
{
  __shared__ float sA2[ND * ND];
  __shared__ float sx[16 * 65];
  const int t = threadIdx.x;
  const int c0 = blockIdx.x * 16, b = blockIdx.y;
#pragma unroll
  for (int q = 0; q < 4; ++q)
    *(float4*)&sA2[q * 1024 + t * 4] =
        *(const float4*)&ah[(size_t)b * ND * ND + q * 1024 + t * 4];
  {
    const int cc = t >> 4, nq = (t & 15) * 4;
    float4 v = *(const float4*)&x2[((size_t)b * IN + c0 + cc) * ND + nq];
    sx[cc * 65 + nq + 0] = v.x; sx[cc * 65 + nq + 1] = v.y;
    sx[cc * 65 + nq + 2] = v.z; sx[cc * 65 + nq + 3] = v.w;
  }
  __syncthreads();
  const int cc = t >> 4, nq = (t & 15) * 4;
  float a0=0.f,a1=0.f,a2=0.f,a3=0.f;
  for (int k = 0; k < ND; ++k) {
    const float xv = sx[cc * 65 + k];
    const float4 av = *(const float4*)&sA2[k * ND + nq];
    a0 += xv*av.x; a1 += xv*av.y; a2 += xv*av.z; a3 += xv*av.w;
  }
  float4 r = make_float4(a0,a1,a2,a3);
  *(float4*)&t2[((size_t)b * IN + c0 + cc) * ND + nq] = r;
}

// ---------------- GC part 4: x2g = relu(gcn_weight @ t2) + x2 --------------
__global__ __launch_bounds__(256) void k_gc4(
    const float* __restrict__ t2, const float* __restrict__ gw,
    const float* __restrict__ x2, float* __restrict__ x2g)
{
  __shared__ float st[IN * ND];    // 64KB
  __shared__ float sw[16 * 257];
  const int t = threadIdx.x;
  const int o0 = blockIdx.x * 16, b = blockIdx.y;
#pragma unroll
  for (int q = 0; q < 16; ++q)
    *(float4*)&st[q * 1024 + t * 4] =
        *(const float4*)&t2[(size_t)b * IN * ND + q * 1024 + t * 4];
  {
    const int oo = t >> 4, iq = (t & 15) * 16;
#pragma unroll
    for (int f = 0; f < 4; ++f) {
      float4 v = *(const float4*)&gw[(size_t)(o0 + oo) * IN + iq + f * 4];
      sw[oo * 257 + iq + f*4 + 0] = v.x; sw[oo * 257 + iq + f*4 + 1] = v.y;
      sw[oo * 257 + iq + f*4 + 2] = v.z; sw[oo * 257 + iq + f*4 + 3] = v.w;
    }
  }
  __syncthreads();
  const int oo = t >> 4, nq = (t & 15) * 4;
  float a0=0.f,a1=0.f,a2=0.f,a3=0.f;
  for (int i = 0; i < IN; ++i) {
    const float w = sw[oo * 257 + i];
    const float4 v = *(const float4*)&st[i * ND + nq];
    a0 += w*v.x; a1 += w*v.y; a2 += w*v.z; a3 += w*v.w;
  }
  const size_t off = ((size_t)b * IN + o0 + oo) * ND + nq;
  const float4 xv = *(const float4*)&x2[off];
  float4 r;
  r.x = fmaxf(a0, 0.f) + xv.x; r.y = fmaxf(a1, 0.f) + xv.y;
  r.z = fmaxf(a2, 0.f) + xv.z; r.w = fmaxf(a3, 0.f) + xv.w;
  *(float4*)&x2g[off] = r;
}

// ---------------- z = W @ v   (W [1024,256], v [b,256,64]) -----------------
__global__ __launch_bounds__(256) void k_zgemm(
    const float* __restrict__ W, const float* __restrict__ v, float* __restrict__ z)
{
  __shared__ float As[16][68];
  __shared__ float Bs[16][64];
  const int t = threadIdx.x, tx = t & 15, ty = t >> 4;
  const int o0 = blockIdx.x * 64, b = blockIdx.y;
  const int aoo = t >> 2, akq = (t & 3) * 4;
  const int bkk = t >> 4, bnq = (t & 15) * 4;
  float acc[4][4] = {};
  for (int k0 = 0; k0 < IN; k0 += 16) {
    {
      float4 w4 = *(const float4*)&W[(size_t)(o0 + aoo) * IN + k0 + akq];
      As[akq+0][aoo] = w4.x; As[akq+1][aoo] = w4.y;
      As[akq+2][aoo] = w4.z; As[akq+3][aoo] = w4.w;
    }
    *(float4*)&Bs[bkk][bnq] = *(const float4*)&v[((size_t)b * IN + k0 + bkk) * ND + bnq];
    __syncthreads();
#pragma unroll
    for (int kk = 0; kk < 16; ++kk) {
      float4 a4 = *(const float4*)&As[kk][ty*4];
      float4 b4 = *(const float4*)&Bs[kk][tx*4];
      float ar[4] = {a4.x,a4.y,a4.z,a4.w}, br[4] = {b4.x,b4.y,b4.z,b4.w};
#pragma unroll
      for (int i = 0; i < 4; ++i)
#pragma unroll
        for (int j = 0; j < 4; ++j) acc[i][j] += ar[i]*br[j];
    }
    __syncthreads();
  }
#pragma unroll
  for (int i = 0; i < 4; ++i) {
    float4 r = make_float4(acc[i][0], acc[i][1], acc[i][2], acc[i][3]);
    *(float4*)&z[((size_t)b * CH + o0 + ty*4 + i) * ND + tx*4] = r;
  }
}

// ---------------- BN stats from z, Spost, G: a=g*rstd, c=beta-mean*a -------
__global__ __launch_bounds__(256) void k_stats(
    const float* __restrict__ z1, const float* __restrict__ z2,
    const float* __restrict__ sp, const float* __restrict__ G,
    const float* __restrict__ gam, const float* __restrict__ bet,
    const float* __restrict__ gam2, const float* __restrict__ bet2,
    float* __restrict__ abc)
{
  const int t = threadIdx.x;
  const int o = blockIdx.x * 4 + (t >> 6), lane = t & 63;
#pragma unroll
  for (int br = 0; br < 2; ++br) {
    const float* z = br ? z2 : z1;
    float macc = 0.f, eacc = 0.f;
    for (int b = 0; b < BB; ++b) {
      const float zv = z[((size_t)b * CH + o) * ND + lane];
      float s1 = zv * sp[b * ND + lane];
      const float* Gb = G + (size_t)b * ND * ND;
      float gz = 0.f;
      for (int k = 0; k < ND; ++k) {
        const float zk = __shfl(zv, k);
        gz += Gb[k * ND + lane] * zk;   // G symmetric -> coalesced
      }
      float q = zv * gz;
#pragma unroll
      for (int off = 32; off; off >>= 1) {
        s1 += __shfl_xor(s1, off);
        q  += __shfl_xor(q, off);
      }
      macc += s1; eacc += q;
    }
    const float inv = 1.f / (float)((size_t)BB * WH);
    const float mean = macc * inv;
    const float var  = eacc * inv - mean * mean;
    const float a = (br ? gam2[o] : gam[o]) * rsqrtf(var + 1e-5f);
    const float c = (br ? bet2[o] : bet[o]) - mean * a;
    if (lane == 0) { abc[br * 2 * CH + o] = a; abc[br * 2 * CH + CH + o] = c; }
  }
}

// ---------------- epilogue: y=z@post^T, BN, relu(relu(.)+x), both outs -----
__global__ __launch_bounds__(256) void k_epilogue(
    const float* __restrict__ z1, const float* __restrict__ z2,
    const float* __restrict__ post, const float* __restrict__ abc,
    const float* __restrict__ x, float* __restrict__ out1, float* __restrict__ out2)
{
  __shared__ float Zt1[64][68], Zt2[64][68], Pt[64][68];   // [n][col], padded
  const int t = threadIdx.x, tx = t & 15, ty = t >> 4;
  const int m0 = blockIdx.x * 64, o0 = blockIdx.y * 64, b = blockIdx.z;
  {
    const int oo = t >> 2, q = t & 3;
    const size_t base1 = ((size_t)b * CH + o0 + oo) * ND + q * 16;
    const size_t base2 = ((size_t)b * WH + m0 + oo) * ND + q * 16;
#pragma unroll
    for (int f = 0; f < 4; ++f) {
      const int n = q * 16 + f * 4;
      float4 v = *(const float4*)&z1[base1 + f * 4];
      Zt1[n+0][oo] = v.x; Zt1[n+1][oo] = v.y; Zt1[n+2][oo] = v.z; Zt1[n+3][oo] = v.w;
      v = *(const float4*)&z2[base1 + f * 4];
      Zt2[n+0][oo] = v.x; Zt2[n+1][oo] = v.y; Zt2[n+2][oo] = v.z; Zt2[n+3][oo] = v.w;
      v = *(const float4*)&post[base2 + f * 4];
      Pt[n+0][oo] = v.x; Pt[n+1][oo] = v.y; Pt[n+2][oo] = v.z; Pt[n+3][oo] = v.w;
    }
  }
  __syncthreads();
  float acc1[4][4] = {}, acc2[4][4] = {};
#pragma unroll 4
  for (int n = 0; n < ND; ++n) {
    float4 v;
    float za[4], zb[4], pv[4];
    v = *(const float4*)&Zt1[n][ty*4]; za[0]=v.x; za[1]=v.y; za[2]=v.z; za[3]=v.w;
    v = *(const float4*)&Zt2[n][ty*4]; zb[0]=v.x; zb[1]=v.y; zb[2]=v.z; zb[3]=v.w;
    v = *(const float4*)&Pt[n][tx*4];  pv[0]=v.x; pv[1]=v.y; pv[2]=v.z; pv[3]=v.w;
#pragma unroll
    for (int i = 0; i < 4; ++i)
#pragma unroll
      for (int j = 0; j < 4; ++j) { acc1[i][j] += za[i]*pv[j]; acc2[i][j] += zb[i]*pv[j]; }
  }
#pragma unroll
  for (int i = 0; i < 4; ++i) {
    const int o = o0 + ty*4 + i;
    const float a1 = abc[o], c1 = abc[CH + o];
    const float a2 = abc[2*CH + o], c2 = abc[3*CH + o];
    const size_t off = ((size_t)b * CH + o) * WH + m0 + tx * 4;
    const float4 xv = *(const float4*)&x[off];
    float4 r1, r2;
    r1.x = fmaxf(fmaxf(a1*acc1[i][0] + c1, 0.f) + xv.x, 0.f);
    r1.y = fmaxf(fmaxf(a1*acc1[i][1] + c1, 0.f) + xv.y, 0.f);
    r1.z = fmaxf(fmaxf(a1*acc1[i][2] + c1, 0.f) + xv.z, 0.f);
    r1.w = fmaxf(fmaxf(a1*acc1[i][3] + c1, 0.f) + xv.w, 0.f);
    r2.x = fmaxf(fmaxf(a2*acc2[i][0] + c2, 0.f) + xv.x, 0.f);
    r2.y = fmaxf(fmaxf(a2*acc2[i][1] + c2, 0.f) + xv.y, 0.f);
    r2.z = fmaxf(fmaxf(a2*acc2[i][2] + c2, 0.f) + xv.z, 0.f);
    r2.w = fmaxf(fmaxf(a2*acc2[i][3] + c2, 0.f) + xv.w, 0.f);
    *(float4*)&out1[off] = r1;
    *(float4*)&out2[off] = r2;
  }
}

// ---------------------------------------------------------------------------
extern "C" void kernel_launch(void* const* d_in, const int* in_sizes, int n_in,
                              void* d_out, int out_size, void* d_ws, size_t ws_size,
                              hipStream_t stream)
{
  (void)in_sizes; (void)n_in; (void)out_size; (void)ws_size;
  const float* x    = (const float*)d_in[0];
  const float* Win  = (const float*)d_in[1];
  const float* bin  = (const float*)d_in[2];
  const float* mp   = (const float*)d_in[3];
  const float* pi0  = (const float*)d_in[4];
  const float* Wa   = (const float*)d_in[5];
  const float* ba   = (const float*)d_in[6];
  const float* Wd   = (const float*)d_in[7];
  const float* bd   = (const float*)d_in[8];
  const float* gw   = (const float*)d_in[9];
  const float* Wo   = (const float*)d_in[10];
  // d_in[11] = b_out  : cancels in BN
  const float* gam  = (const float*)d_in[12];
  const float* bet  = (const float*)d_in[13];
  const float* Wo2  = (const float*)d_in[14];
  // d_in[15] = b_out2 : cancels in BN
  const float* gam2 = (const float*)d_in[16];
  const float* bet2 = (const float*)d_in[17];

  float* ws    = (float*)d_ws;
  float* x1    = ws + OFF_X1;
  float* postb = ws + OFF_PST;
  float* mu    = ws + OFF_MU;     // doubles as x2 after EM
  float* sp    = ws + OFF_SP;
  float* piw   = ws + OFF_PI;
  float* mup   = ws + OFF_MUP;
  float* gp    = ws + OFF_GP;
  float* G     = ws + OFF_G;
  float* xa    = ws + OFF_XA;
  float* dvm5  = ws + OFF_DV;
  float* ah    = ws + OFF_AH;
  float* t2    = ws + OFF_T2;
  float* x2g   = ws + OFF_X2G;
  float* z1    = ws + OFF_Z1;
  float* z2    = ws + OFF_Z2;
  float* abc   = ws + OFF_ABC;
  float* out1  = (float*)d_out;
  float* out2  = out1 + TOT;

  k_gemm_x1<<<dim3(WH/128, IN/128, BB), 256, 0, stream>>>(x, Win, bin, x1);
  k_init<<<dim3(256), 256, 0, stream>>>(mp, pi0, mu, piw);
  for (int it = 0; it < 3; ++it) {
    k_lik<<<dim3(WH/64, BB), 256, 0, stream>>>(x1, mu, postb);
    k_softmax<<<dim3(BB*WH/4), 256, 0, stream>>>(postb, piw);
    k_spost<<<dim3(BB), 1024, 0, stream>>>(postb, sp, piw);
    k_mu_part<<<dim3(16, 4, BB), 256, 0, stream>>>(x1, postb, mup);
    k_mu_reduce<<<dim3(256), 256, 0, stream>>>(mup, sp, mu);
  }
  k_G_part<<<dim3(16, BB), 256, 0, stream>>>(postb, gp);
  k_G_reduce<<<dim3(64), 256, 0, stream>>>(gp, G);
  k_gc1<<<dim3(8, BB), 256, 0, stream>>>(mu, Wa, ba, Wd, bd, xa, dvm5);
  k_gc2<<<dim3(BB), 256, 0, stream>>>(xa, dvm5, ah);
  k_gc3<<<dim3(16, BB), 256, 0, stream>>>(mu, ah, t2);
  k_gc4<<<dim3(16, BB), 256, 0, stream>>>(t2, gw, mu, x2g);
  k_zgemm<<<dim3(16, BB), 256, 0, stream>>>(Wo2, mu, z2);
  k_zgemm<<<dim3(16, BB), 256, 0, stream>>>(Wo, x2g, z1);
  k_stats<<<dim3(256), 256, 0, stream>>>(z1, z2, sp, G, gam, bet, gam2, bet2, abc);
  k_epilogue<<<dim3(WH/64, CH/64, BB), 256, 0, stream>>>(z1, z2, postb, abc, x, out1, out2);
}

// Round 2
// 330.392 us; speedup vs baseline: 1.7952x; 1.7952x over previous
//
#include <hip/hip_runtime.h>
#include <math.h>

// ---------------------------------------------------------------------------
// Intra_graph forward, MI355X. Round 2: bf16 MFMA everywhere.
//  * all big GEMMs use mfma_f32_16x16x32_bf16 with NT layouts (both operands
//    k-contiguous); A/B use the SAME per-lane k-map -> layout-permutation safe
//  * x pre-transposed once to bf16 xt[m][i]; x1 kept in both [c][m] and [m][c]
//  * fused lik+softmax kernel emits post in both [m][n] and [n][m] (bf16)
//  * epilogue: no-LDS MFMA (z,post L2-resident) + BN + residual relu, fused
//  * big scratch (xt, mu-partials, gp, z1, z2) lives in d_out (dead before
//    the epilogue overwrites it); ws usage ~22.6 MB
// ---------------------------------------------------------------------------

typedef unsigned short u16;
typedef short s16x8 __attribute__((ext_vector_type(8)));
typedef float f32x4 __attribute__((ext_vector_type(4)));

constexpr int BB  = 4;
constexpr int CH  = 1024;
constexpr int IN  = 256;
constexpr int ND  = 64;
constexpr int WH  = 4096;
constexpr int DCN = 128;
constexpr size_t TOT = (size_t)BB * CH * WH;

__device__ inline u16 f2bf(float f) {
  unsigned u = __float_as_uint(f);
  return (u16)((u + 0x7fffu + ((u >> 16) & 1u)) >> 16);
}
__device__ inline float bfl(unsigned u) { return __uint_as_float(u << 16); }
__device__ inline float bfh(unsigned u) { return __uint_as_float(u & 0xffff0000u); }
__device__ inline s16x8 ld8(const u16* p) { return *(const s16x8*)p; }
#define MFMA16(a, b, c) __builtin_amdgcn_mfma_f32_16x16x32_bf16(a, b, c, 0, 0, 0)

// ---------------- transpose + bf16: xt[b][m][i] <- x[b][i][m] --------------
__global__ __launch_bounds__(256) void k_tr(const float* __restrict__ x,
                                            u16* __restrict__ xt) {
  __shared__ float lt[64 * 65];
  const int t = threadIdx.x, bb = blockIdx.z;
  const int m0 = blockIdx.x * 64, i0 = blockIdx.y * 64;
#pragma unroll
  for (int r4 = 0; r4 < 4; ++r4) {
    const int i = r4 * 16 + (t >> 4), mq = (t & 15) * 4;
    float4 v = *(const float4*)&x[((size_t)bb * CH + i0 + i) * WH + m0 + mq];
    lt[(mq + 0) * 65 + i] = v.x; lt[(mq + 1) * 65 + i] = v.y;
    lt[(mq + 2) * 65 + i] = v.z; lt[(mq + 3) * 65 + i] = v.w;
  }
  __syncthreads();
#pragma unroll
  for (int r4 = 0; r4 < 4; ++r4) {
    const int m = r4 * 16 + (t >> 4), i4 = (t & 15) * 4;
    ushort4 o;
    o.x = f2bf(lt[m * 65 + i4 + 0]); o.y = f2bf(lt[m * 65 + i4 + 1]);
    o.z = f2bf(lt[m * 65 + i4 + 2]); o.w = f2bf(lt[m * 65 + i4 + 3]);
    *(ushort4*)&xt[((size_t)bb * WH + m0 + m) * CH + i0 + i4] = o;
  }
}

// ---------------- init: Winb bf16, mu_t bf16 [b][n][c], piw ----------------
__global__ void k_init(const float* __restrict__ Win, const float* __restrict__ mp,
                       const float* __restrict__ pi0, u16* __restrict__ Winb,
                       u16* __restrict__ mu_t, float* __restrict__ piw) {
  int idx = blockIdx.x * 256 + threadIdx.x;
  if (idx < IN * CH) { Winb[idx] = f2bf(Win[idx]); return; }
  int j = idx - IN * CH;
  if (j < BB * ND * IN) {
    int bb = j >> 14, n = (j >> 8) & 63, c = j & 255;
    mu_t[((size_t)(bb * ND + n)) * IN + c] = f2bf(mp[c * ND + n]);
    return;
  }
  j -= BB * ND * IN;
  if (j < BB * ND) piw[j] = pi0[j & 63];
}

// ---------------- generic NT bf16 GEMM: C[M][N] = A[M][K] . B[N][K]^T ------
// grid (M/128, N/128, BB), block 256 = 4 waves, wave computes 64x64.
__global__ __launch_bounds__(256) void k_nt(
    const u16* __restrict__ A, const u16* __restrict__ B, u16* __restrict__ C,
    const float* __restrict__ bias, int M, int N, int K,
    size_t sA, size_t sB, size_t sC, int biasCol) {
  const int t = threadIdx.x, w = t >> 6, lr = t & 15, lg = (t >> 4) & 3;
  const int bb = blockIdx.z;
  const int r0 = blockIdx.x * 128 + (w >> 1) * 64;
  const int c0 = blockIdx.y * 128 + (w & 1) * 64;
  A += (size_t)bb * sA; B += (size_t)bb * sB; C += (size_t)bb * sC;
  f32x4 acc[4][4];
#pragma unroll
  for (int i = 0; i < 4; ++i)
#pragma unroll
    for (int j = 0; j < 4; ++j) acc[i][j] = (f32x4){0.f, 0.f, 0.f, 0.f};
  const u16* ap = A + (size_t)(r0 + lr) * K + lg * 8;
  const u16* bp = B + (size_t)(c0 + lr) * K + lg * 8;
#pragma unroll 2
  for (int k0 = 0; k0 < K; k0 += 32) {
    s16x8 af[4], bf[4];
#pragma unroll
    for (int i = 0; i < 4; ++i) af[i] = ld8(ap + (size_t)i * 16 * K + k0);
#pragma unroll
    for (int j = 0; j < 4; ++j) bf[j] = ld8(bp + (size_t)j * 16 * K + k0);
#pragma unroll
    for (int i = 0; i < 4; ++i)
#pragma unroll
      for (int j = 0; j < 4; ++j) acc[i][j] = MFMA16(af[i], bf[j], acc[i][j]);
  }
#pragma unroll
  for (int i = 0; i < 4; ++i)
#pragma unroll
    for (int j = 0; j < 4; ++j)
#pragma unroll
      for (int r = 0; r < 4; ++r) {
        const int row = r0 + i * 16 + lg * 4 + r;
        const int col = c0 + j * 16 + lr;
        float v = acc[i][j][r] + (biasCol ? bias[col] : bias[row]);
        C[(size_t)row * N + col] = f2bf(v);
      }
}

// ---------------- fused lik + softmax -> post_mn bf16, post_t bf16 ---------
// grid (64 m-tiles, BB), block 256; wave w owns m-rows [w*16, w*16+16).
__global__ __launch_bounds__(256) void k_em1(
    const u16* __restrict__ x1t, const u16* __restrict__ mu_t,
    const float* __restrict__ piw, u16* __restrict__ post_mn,
    u16* __restrict__ post_t) {
  __shared__ u16 trans[64 * 72];
  const int t = threadIdx.x, w = t >> 6, lr = t & 15, lg = (t >> 4) & 3;
  const int mt = blockIdx.x * 64, bb = blockIdx.y;
  f32x4 acc[4];
#pragma unroll
  for (int f = 0; f < 4; ++f) acc[f] = (f32x4){0.f, 0.f, 0.f, 0.f};
  const u16* ap = x1t + ((size_t)bb * WH + mt + w * 16 + lr) * IN + lg * 8;
  const u16* bp = mu_t + ((size_t)bb * ND + lr) * IN + lg * 8;
#pragma unroll
  for (int k0 = 0; k0 < IN; k0 += 32) {
    s16x8 a = ld8(ap + k0);
#pragma unroll
    for (int f = 0; f < 4; ++f)
      acc[f] = MFMA16(a, ld8(bp + f * 16 * IN + k0), acc[f]);
  }
  float pi_[4];
#pragma unroll
  for (int f = 0; f < 4; ++f) pi_[f] = piw[bb * ND + f * 16 + lr];
#pragma unroll
  for (int r = 0; r < 4; ++r) {
    float v0 = acc[0][r], v1 = acc[1][r], v2 = acc[2][r], v3 = acc[3][r];
    float mx = fmaxf(fmaxf(v0, v1), fmaxf(v2, v3));
    mx = fmaxf(mx, __shfl_xor(mx, 1)); mx = fmaxf(mx, __shfl_xor(mx, 2));
    mx = fmaxf(mx, __shfl_xor(mx, 4)); mx = fmaxf(mx, __shfl_xor(mx, 8));
    float e0 = __expf(v0 - mx) * pi_[0], e1 = __expf(v1 - mx) * pi_[1];
    float e2 = __expf(v2 - mx) * pi_[2], e3 = __expf(v3 - mx) * pi_[3];
    float s = e0 + e1 + e2 + e3;
    s += __shfl_xor(s, 1); s += __shfl_xor(s, 2);
    s += __shfl_xor(s, 4); s += __shfl_xor(s, 8);
    const float inv = 1.f / (1e-18f + s);
    const int mloc = w * 16 + lg * 4 + r;
    const size_t gbase = ((size_t)bb * WH + mt + mloc) * ND + lr;
    u16 q0 = f2bf(e0 * inv), q1 = f2bf(e1 * inv);
    u16 q2 = f2bf(e2 * inv), q3 = f2bf(e3 * inv);
    post_mn[gbase + 0]  = q0; post_mn[gbase + 16] = q1;
    post_mn[gbase + 32] = q2; post_mn[gbase + 48] = q3;
    trans[(0 + lr) * 72 + mloc]  = q0; trans[(16 + lr) * 72 + mloc] = q1;
    trans[(32 + lr) * 72 + mloc] = q2; trans[(48 + lr) * 72 + mloc] = q3;
  }
  __syncthreads();
  {
    const int n = t >> 2, q = t & 3;
    const u16* s8 = &trans[n * 72 + q * 16];
    uint4 u0 = *(const uint4*)s8;
    uint4 u1 = *(const uint4*)(s8 + 8);
    u16* dst = post_t + ((size_t)bb * ND + n) * WH + mt + q * 16;
    *(uint4*)dst = u0;
    *(uint4*)(dst + 8) = u1;
  }
}

// ---------------- Spost + pi from post_t -----------------------------------
__global__ __launch_bounds__(256) void k_spost(const u16* __restrict__ post_t,
                                               float* __restrict__ sp,
                                               float* __restrict__ piw) {
  __shared__ float red[4];
  const int t = threadIdx.x, bb = blockIdx.x >> 6, n = blockIdx.x & 63;
  const u16* row = post_t + ((size_t)(bb * ND + n)) * WH + t * 16;
  uint4 v0 = *(const uint4*)row;
  uint4 v1 = *(const uint4*)(row + 8);
  float s = bfl(v0.x) + bfh(v0.x) + bfl(v0.y) + bfh(v0.y) +
            bfl(v0.z) + bfh(v0.z) + bfl(v0.w) + bfh(v0.w) +
            bfl(v1.x) + bfh(v1.x) + bfl(v1.y) + bfh(v1.y) +
            bfl(v1.z) + bfh(v1.z) + bfl(v1.w) + bfh(v1.w);
#pragma unroll
  for (int o = 32; o; o >>= 1) s += __shfl_xor(s, o);
  if ((t & 63) == 0) red[t >> 6] = s;
  __syncthreads();
  if (t == 0) {
    float a = red[0] + red[1] + red[2] + red[3];
    sp[bb * ND + n] = a;
    piw[bb * ND + n] = a * (1.f / (float)WH);
  }
}

// ---------------- mu partials: mup[ch][b][c][n] = x1 . post_t^T ------------
// grid (32 chunks, BB), block 256; wave w = c-tile; chunk = 128 m.
__global__ __launch_bounds__(256) void k_em2(const u16* __restrict__ x1,
                                             const u16* __restrict__ post_t,
                                             float* __restrict__ mup) {
  const int t = threadIdx.x, w = t >> 6, lr = t & 15, lg = (t >> 4) & 3;
  const int chunk = blockIdx.x, bb = blockIdx.y;
  f32x4 acc[4][4];
#pragma unroll
  for (int i = 0; i < 4; ++i)
#pragma unroll
    for (int j = 0; j < 4; ++j) acc[i][j] = (f32x4){0.f, 0.f, 0.f, 0.f};
  const u16* ap = x1 + ((size_t)bb * IN + w * 64 + lr) * WH + chunk * 128 + lg * 8;
  const u16* bp = post_t + ((size_t)bb * ND + lr) * WH + chunk * 128 + lg * 8;
#pragma unroll
  for (int ks = 0; ks < 4; ++ks) {
    s16x8 af[4], bf[4];
#pragma unroll
    for (int i = 0; i < 4; ++i) af[i] = ld8(ap + (size_t)i * 16 * WH + ks * 32);
#pragma unroll
    for (int j = 0; j < 4; ++j) bf[j] = ld8(bp + (size_t)j * 16 * WH + ks * 32);
#pragma unroll
    for (int i = 0; i < 4; ++i)
#pragma unroll
      for (int j = 0; j < 4; ++j) acc[i][j] = MFMA16(af[i], bf[j], acc[i][j]);
  }
#pragma unroll
  for (int i = 0; i < 4; ++i)
#pragma unroll
    for (int j = 0; j < 4; ++j)
#pragma unroll
      for (int r = 0; r < 4; ++r) {
        const int c = w * 64 + i * 16 + lg * 4 + r, n = j * 16 + lr;
        mup[((size_t)chunk * BB + bb) * (IN * ND) + c * ND + n] = acc[i][j][r];
      }
}

// ---------------- mu = sum(mup)/sp -> mu f32 [b][c][n], mu_t bf16 [b][n][c]
__global__ void k_mu_red(const float* __restrict__ mup, const float* __restrict__ sp,
                         float* __restrict__ mu, u16* __restrict__ mu_t) {
  const int idx = blockIdx.x * 256 + threadIdx.x;  // 65536
  const int i16k = idx & 16383, bb = idx >> 14, c = (idx >> 6) & 255, n = idx & 63;
  float s = 0.f;
#pragma unroll
  for (int ch = 0; ch < 32; ++ch)
    s += mup[(size_t)ch * (BB * IN * ND) + bb * (IN * ND) + i16k];
  const float v = s / (1e-18f + sp[bb * ND + n]);
  mu[idx] = v;
  mu_t[((size_t)(bb * ND + n)) * IN + c] = f2bf(v);
}

// ---------------- G partials (f32 VALU, swizzled LDS) ----------------------
__global__ __launch_bounds__(256) void k_G(const u16* __restrict__ post_t,
                                           float* __restrict__ gp) {
  __shared__ float P[64 * 256];
  const int t = threadIdx.x, chunk = blockIdx.x, bb = blockIdx.y;
  {
    const int n = t >> 2, mb = (t & 3) * 64;
    const u16* src = post_t + ((size_t)(bb * ND + n)) * WH + chunk * 256 + mb;
#pragma unroll
    for (int q = 0; q < 8; ++q) {
      uint4 v = *(const uint4*)(src + q * 8);
      float f[8] = {bfl(v.x), bfh(v.x), bfl(v.y), bfh(v.y),
                    bfl(v.z), bfh(v.z), bfl(v.w), bfh(v.w)};
#pragma unroll
      for (int e = 0; e < 8; ++e) {
        const int m = mb + q * 8 + e;
        P[n * 256 + ((m + n) & 255)] = f[e];
      }
    }
  }
  __syncthreads();
  const int n1 = t & 63, g = t >> 6;
  float acc[16];
#pragma unroll
  for (int j = 0; j < 16; ++j) acc[j] = 0.f;
  for (int m = 0; m < 256; ++m) {
    const float v1 = P[n1 * 256 + ((m + n1) & 255)];
#pragma unroll
    for (int j = 0; j < 16; ++j) {
      const int n2 = g * 16 + j;
      acc[j] += v1 * P[n2 * 256 + ((m + n2) & 255)];
    }
  }
#pragma unroll
  for (int j = 0; j < 16; ++j)
    gp[((size_t)chunk * BB + bb) * (ND * ND) + n1 * ND + g * 16 + j] = acc[j];
}

__global__ void k_G_reduce(const float* __restrict__ gp, float* __restrict__ G) {
  const int idx = blockIdx.x * 256 + threadIdx.x;  // grid 64 -> BB*ND*ND
  float s = 0.f;
#pragma unroll
  for (int kc = 0; kc < 16; ++kc) s += gp[(size_t)kc * (BB * ND * ND) + idx];
  G[idx] = s;
}

// ---------------- GC layer part 1 (unchanged, f32) -------------------------
__global__ __launch_bounds__(256) void k_gc1(
    const float* __restrict__ x2, const float* __restrict__ Wa, const float* __restrict__ ba,
    const float* __restrict__ Wd, const float* __restrict__ bd,
    float* __restrict__ xa, float* __restrict__ dvm5) {
  __shared__ float sx2[IN * ND];
  __shared__ float ssx[IN];
  const int t = threadIdx.x;
  const int dc0 = blockIdx.x * 16, bb = blockIdx.y;
  const float* src = x2 + (size_t)bb * IN * ND;
#pragma unroll
  for (int q = 0; q < 16; ++q)
    *(float4*)&sx2[q * 1024 + t * 4] = *(const float4*)&src[q * 1024 + t * 4];
  __syncthreads();
  {
    float s = 0.f;
#pragma unroll
    for (int q = 0; q < 16; ++q) {
      const int n4 = ((q + (t & 15)) & 15) * 4;
      float4 v = *(const float4*)&sx2[t * 64 + n4];
      s += v.x + v.y + v.z + v.w;
    }
    ssx[t] = s;
  }
  __syncthreads();
  if (t < 16) {
    const int dc = dc0 + t;
    float a = 0.f;
    for (int i = 0; i < IN; ++i) a += Wd[dc * IN + i] * ssx[i];
    const float xm = a * (1.f / ND) + bd[dc];
    dvm5[bb * DCN + dc] = 1.f / (1.f + __expf(-xm)) - 0.5f;
  }
  const int dc = dc0 + (t >> 4), j0 = (t & 15) * 4;
  float a0 = 0.f, a1 = 0.f, a2 = 0.f, a3 = 0.f;
  for (int i = 0; i < IN; ++i) {
    const float wv = Wa[dc * IN + i];
    const float4 v = *(const float4*)&sx2[i * 64 + j0];
    a0 += wv * v.x; a1 += wv * v.y; a2 += wv * v.z; a3 += wv * v.w;
  }
  const float bav = ba[dc];
  float4 r = make_float4(a0 + bav, a1 + bav, a2 + bav, a3 + bav);
  *(float4*)&xa[((size_t)bb * DCN + dc) * ND + j0] = r;
}

// ---------------- GC part 2 (unchanged) ------------------------------------
__global__ __launch_bounds__(256) void k_gc2(
    const float* __restrict__ xa, const float* __restrict__ dvm5, float* __restrict__ ah) {
  __shared__ float sxa[DCN * ND];
  __shared__ float sdv[DCN];
  __shared__ float su[ND];
  __shared__ float sdeg[ND];
  __shared__ float sA[ND * 65];
  const int t = threadIdx.x, bb = blockIdx.x;
  const float* src = xa + (size_t)bb * DCN * ND;
#pragma unroll
  for (int q = 0; q < 8; ++q)
    *(float4*)&sxa[q * 1024 + t * 4] = *(const float4*)&src[q * 1024 + t * 4];
  if (t < DCN) sdv[t] = dvm5[bb * DCN + t];
  __syncthreads();
  if (t < ND) {
    float s = 0.f;
    for (int dc = 0; dc < DCN; ++dc) s += sxa[dc * ND + t];
    su[t] = s;
  }
  __syncthreads();
  const int n1 = t & 63, g = t >> 6;
  {
    const float u1 = su[n1];
    float acc[16];
#pragma unroll
    for (int j = 0; j < 16; ++j) acc[j] = 0.5f * u1 * su[g * 16 + j];
    for (int dc = 0; dc < DCN; ++dc) {
      const float v = sxa[dc * ND + n1] * sdv[dc];
      const float* row = &sxa[dc * ND + g * 16];
#pragma unroll
      for (int j = 0; j < 16; ++j) acc[j] += v * row[j];
    }
#pragma unroll
    for (int j = 0; j < 16; ++j) {
      const int n2 = g * 16 + j;
      sA[n1 * 65 + n2] = fmaxf(acc[j], 0.f) + (n1 == n2 ? 1.f : 0.f);
    }
  }
  __syncthreads();
  if (t < ND) {
    float s = 0.f;
    for (int m = 0; m < ND; ++m) s += sA[m * 65 + t];
    sdeg[t] = rsqrtf(s);
  }
  __syncthreads();
  {
    const int r = t >> 2, cq = (t & 3) * 16;
    const float dr = sdeg[r];
#pragma unroll
    for (int f = 0; f < 4; ++f) {
      const int c = cq + f * 4;
      float4 o;
      o.x = dr * sA[r * 65 + c + 0] * sdeg[c + 0];
      o.y = dr * sA[r * 65 + c + 1] * sdeg[c + 1];
      o.z = dr * sA[r * 65 + c + 2] * sdeg[c + 2];
      o.w = dr * sA[r * 65 + c + 3] * sdeg[c + 3];
      *(float4*)&ah[((size_t)bb * ND + r) * ND + c] = o;
    }
  }
}

// ---------------- GC part 3 (unchanged) ------------------------------------
__global__ __launch_bounds__(256) void k_gc3(
    const float* __restrict__ x2, const float* __restrict__ ah, float* __restrict__ t2) {
  __shared__ float sA2[ND * ND];
  __shared__ float sx[16 * 65];
  const int t = threadIdx.x;
  const int c0 = blockIdx.x * 16, bb = blockIdx.y;
#pragma unroll
  for (int q = 0; q < 4; ++q)
    *(float4*)&sA2[q * 1024 + t * 4] =
        *(const float4*)&ah[(size_t)bb * ND * ND + q * 1024 + t * 4];
  {
    const int cc = t >> 4, nq = (t & 15) * 4;
    float4 v = *(const float4*)&x2[((size_t)bb * IN + c0 + cc) * ND + nq];
    sx[cc * 65 + nq + 0] = v.x; sx[cc * 65 + nq + 1] = v.y;
    sx[cc * 65 + nq + 2] = v.z; sx[cc * 65 + nq + 3] = v.w;
  }
  __syncthreads();
  const int cc = t >> 4, nq = (t & 15) * 4;
  float a0 = 0.f, a1 = 0.f, a2 = 0.f, a3 = 0.f;
  for (int k = 0; k < ND; ++k) {
    const float xv = sx[cc * 65 + k];
    const float4 av = *(const float4*)&sA2[k * ND + nq];
    a0 += xv * av.x; a1 += xv * av.y; a2 += xv * av.z; a3 += xv * av.w;
  }
  float4 r = make_float4(a0, a1, a2, a3);
  *(float4*)&t2[((size_t)bb * IN + c0 + cc) * ND + nq] = r;
}

// ---------------- GC part 4 (unchanged) ------------------------------------
__global__ __launch_bounds__(256) void k_gc4(
    const float* __restrict__ t2, const float* __restrict__ gw,
    const float* __restrict__ x2, float* __restrict__ x2g) {
  __shared__ float st[IN * ND];
  __shared__ float sw[16 * 257];
  const int t = threadIdx.x;
  const int o0 = blockIdx.x * 16, bb = blockIdx.y;
#pragma unroll
  for (int q = 0; q < 16; ++q)
    *(float4*)&st[q * 1024 + t * 4] =
        *(const float4*)&t2[(size_t)bb * IN * ND + q * 1024 + t * 4];
  {
    const int oo = t >> 4, iq = (t & 15) * 16;
#pragma unroll
    for (int f = 0; f < 4; ++f) {
      float4 v = *(const float4*)&gw[(size_t)(o0 + oo) * IN + iq + f * 4];
      sw[oo * 257 + iq + f * 4 + 0] = v.x; sw[oo * 257 + iq + f * 4 + 1] = v.y;
      sw[oo * 257 + iq + f * 4 + 2] = v.z; sw[oo * 257 + iq + f * 4 + 3] = v.w;
    }
  }
  __syncthreads();
  const int oo = t >> 4, nq = (t & 15) * 4;
  float a0 = 0.f, a1 = 0.f, a2 = 0.f, a3 = 0.f;
  for (int i = 0; i < IN; ++i) {
    const float wv = sw[oo * 257 + i];
    const float4 v = *(const float4*)&st[i * ND + nq];
    a0 += wv * v.x; a1 += wv * v.y; a2 += wv * v.z; a3 += wv * v.w;
  }
  const size_t off = ((size_t)bb * IN + o0 + oo) * ND + nq;
  const float4 xv = *(const float4*)&x2[off];
  float4 r;
  r.x = fmaxf(a0, 0.f) + xv.x; r.y = fmaxf(a1, 0.f) + xv.y;
  r.z = fmaxf(a2, 0.f) + xv.z; r.w = fmaxf(a3, 0.f) + xv.w;
  *(float4*)&x2g[off] = r;
}

// ---------------- z = W @ v (f32) + zb bf16 copy ---------------------------
__global__ __launch_bounds__(256) void k_zgemm(
    const float* __restrict__ W, const float* __restrict__ v,
    float* __restrict__ z, u16* __restrict__ zb) {
  __shared__ float As[16][68];
  __shared__ float Bs[16][64];
  const int t = threadIdx.x, tx = t & 15, ty = t >> 4;
  const int o0 = blockIdx.x * 64, bb = blockIdx.y;
  const int aoo = t >> 2, akq = (t & 3) * 4;
  const int bkk = t >> 4, bnq = (t & 15) * 4;
  float acc[4][4] = {};
  for (int k0 = 0; k0 < IN; k0 += 16) {
    {
      float4 w4 = *(const float4*)&W[(size_t)(o0 + aoo) * IN + k0 + akq];
      As[akq + 0][aoo] = w4.x; As[akq + 1][aoo] = w4.y;
      As[akq + 2][aoo] = w4.z; As[akq + 3][aoo] = w4.w;
    }
    *(float4*)&Bs[bkk][bnq] = *(const float4*)&v[((size_t)bb * IN + k0 + bkk) * ND + bnq];
    __syncthreads();
#pragma unroll
    for (int kk = 0; kk < 16; ++kk) {
      float4 a4 = *(const float4*)&As[kk][ty * 4];
      float4 b4 = *(const float4*)&Bs[kk][tx * 4];
      float ar[4] = {a4.x, a4.y, a4.z, a4.w}, br[4] = {b4.x, b4.y, b4.z, b4.w};
#pragma unroll
      for (int i = 0; i < 4; ++i)
#pragma unroll
        for (int j = 0; j < 4; ++j) acc[i][j] += ar[i] * br[j];
    }
    __syncthreads();
  }
#pragma unroll
  for (int i = 0; i < 4; ++i) {
    float4 r = make_float4(acc[i][0], acc[i][1], acc[i][2], acc[i][3]);
    const size_t off = ((size_t)bb * CH + o0 + ty * 4 + i) * ND + tx * 4;
    *(float4*)&z[off] = r;
    ushort4 h;
    h.x = f2bf(r.x); h.y = f2bf(r.y); h.z = f2bf(r.z); h.w = f2bf(r.w);
    *(ushort4*)&zb[off] = h;
  }
}

// ---------------- BN stats (unchanged) -------------------------------------
__global__ __launch_bounds__(256) void k_stats(
    const float* __restrict__ z1, const float* __restrict__ z2,
    const float* __restrict__ sp, const float* __restrict__ G,
    const float* __restrict__ gam, const float* __restrict__ bet,
    const float* __restrict__ gam2, const float* __restrict__ bet2,
    float* __restrict__ abc) {
  const int t = threadIdx.x;
  const int o = blockIdx.x * 4 + (t >> 6), lane = t & 63;
#pragma unroll
  for (int br = 0; br < 2; ++br) {
    const float* z = br ? z2 : z1;
    float macc = 0.f, eacc = 0.f;
    for (int bb = 0; bb < BB; ++bb) {
      const float zv = z[((size_t)bb * CH + o) * ND + lane];
      float s1 = zv * sp[bb * ND + lane];
      const float* Gb = G + (size_t)bb * ND * ND;
      float gz = 0.f;
      for (int k = 0; k < ND; ++k) {
        const float zk = __shfl(zv, k);
        gz += Gb[k * ND + lane] * zk;
      }
      float q = zv * gz;
#pragma unroll
      for (int off = 32; off; off >>= 1) {
        s1 += __shfl_xor(s1, off);
        q  += __shfl_xor(q, off);
      }
      macc += s1; eacc += q;
    }
    const float inv = 1.f / (float)((size_t)BB * WH);
    const float mean = macc * inv;
    const float var  = eacc * inv - mean * mean;
    const float a = (br ? gam2[o] : gam[o]) * rsqrtf(var + 1e-5f);
    const float c = (br ? bet2[o] : bet[o]) - mean * a;
    if (lane == 0) { abc[br * 2 * CH + o] = a; abc[br * 2 * CH + CH + o] = c; }
  }
}

// ---------------- epilogue: MFMA y=z.post^T, BN, residual relus ------------
// grid (16 m-tiles(256), 16 o-tiles(64), BB), block 256; wave w: m-sub w*64.
__global__ __launch_bounds__(256) void k_epi(
    const u16* __restrict__ zb1, const u16* __restrict__ zb2,
    const u16* __restrict__ post, const float* __restrict__ abc,
    const float* __restrict__ x, float* __restrict__ out1, float* __restrict__ out2) {
  const int t = threadIdx.x, w = t >> 6, lr = t & 15, lg = (t >> 4) & 3;
  const int m0 = blockIdx.x * 256 + w * 64, o0 = blockIdx.y * 64, bb = blockIdx.z;
  f32x4 acc1[4][4], acc2[4][4];
#pragma unroll
  for (int i = 0; i < 4; ++i)
#pragma unroll
    for (int j = 0; j < 4; ++j) {
      acc1[i][j] = (f32x4){0.f, 0.f, 0.f, 0.f};
      acc2[i][j] = (f32x4){0.f, 0.f, 0.f, 0.f};
    }
  const u16* z1p = zb1 + ((size_t)bb * CH + o0 + lr) * ND + lg * 8;
  const u16* z2p = zb2 + ((size_t)bb * CH + o0 + lr) * ND + lg * 8;
  const u16* pp  = post + ((size_t)bb * WH + m0 + lr) * ND + lg * 8;
#pragma unroll
  for (int ks = 0; ks < 2; ++ks) {
    s16x8 a1[4], a2[4], bq[4];
#pragma unroll
    for (int i = 0; i < 4; ++i) {
      a1[i] = ld8(z1p + i * 16 * ND + ks * 32);
      a2[i] = ld8(z2p + i * 16 * ND + ks * 32);
    }
#pragma unroll
    for (int j = 0; j < 4; ++j) bq[j] = ld8(pp + j * 16 * ND + ks * 32);
#pragma unroll
    for (int i = 0; i < 4; ++i)
#pragma unroll
      for (int j = 0; j < 4; ++j) {
        acc1[i][j] = MFMA16(a1[i], bq[j], acc1[i][j]);
        acc2[i][j] = MFMA16(a2[i], bq[j], acc2[i][j]);
      }
  }
#pragma unroll
  for (int i = 0; i < 4; ++i)
#pragma unroll
    for (int r = 0; r < 4; ++r) {
      const int o = o0 + i * 16 + lg * 4 + r;
      const float a1v = abc[o], c1v = abc[CH + o];
      const float a2v = abc[2 * CH + o], c2v = abc[3 * CH + o];
      const size_t base = ((size_t)bb * CH + o) * WH + m0 + lr;
#pragma unroll
      for (int j = 0; j < 4; ++j) {
        const size_t off = base + j * 16;
        const float xv = x[off];
        out1[off] = fmaxf(fmaxf(a1v * acc1[i][j][r] + c1v, 0.f) + xv, 0.f);
        out2[off] = fmaxf(fmaxf(a2v * acc2[i][j][r] + c2v, 0.f) + xv, 0.f);
      }
    }
}

// ---------------------------------------------------------------------------
extern "C" void kernel_launch(void* const* d_in, const int* in_sizes, int n_in,
                              void* d_out, int out_size, void* d_ws, size_t ws_size,
                              hipStream_t stream) {
  (void)in_sizes; (void)n_in; (void)out_size; (void)ws_size;
  const float* x    = (const float*)d_in[0];
  const float* Win  = (const float*)d_in[1];
  const float* bin  = (const float*)d_in[2];
  const float* mp   = (const float*)d_in[3];
  const float* pi0  = (const float*)d_in[4];
  const float* Wa   = (const float*)d_in[5];
  const float* ba   = (const float*)d_in[6];
  const float* Wd   = (const float*)d_in[7];
  const float* bd   = (const float*)d_in[8];
  const float* gw   = (const float*)d_in[9];
  const float* Wo   = (const float*)d_in[10];
  const float* gam  = (const float*)d_in[12];
  const float* bet  = (const float*)d_in[13];
  const float* Wo2  = (const float*)d_in[14];
  const float* gam2 = (const float*)d_in[16];
  const float* bet2 = (const float*)d_in[17];

  char* ob = (char*)d_out;
  char* w  = (char*)d_ws;
  // scratch in d_out (all dead before k_epi writes outputs):
  u16*   xt  = (u16*)(ob + 0);           // 32 MB
  float* mup = (float*)(ob + 33554432);  // 8 MB   (32 chunks)
  float* gp  = (float*)(ob + 41943040);  // 1 MB
  float* z1  = (float*)(ob + 42991616);  // 1 MB
  float* z2  = (float*)(ob + 44040192);  // 1 MB
  // ws (~22.6 MB):
  u16*   x1   = (u16*)(w + 0);
  u16*   x1t  = (u16*)(w + 8388608);
  u16*   Winb = (u16*)(w + 16777216);
  u16*   mu_t = (u16*)(w + 17301504);
  u16*   pmn  = (u16*)(w + 17432576);
  u16*   pt   = (u16*)(w + 19529728);
  float* sp   = (float*)(w + 21626880);
  float* piw  = (float*)(w + 21627904);
  float* mu   = (float*)(w + 21628928);
  float* xa   = (float*)(w + 21891072);
  float* dv   = (float*)(w + 22022144);
  float* ah   = (float*)(w + 22024192);
  float* t2   = (float*)(w + 22089728);
  float* x2g  = (float*)(w + 22351872);
  u16*   zb1  = (u16*)(w + 22614016);
  u16*   zb2  = (u16*)(w + 23138304);
  float* abc  = (float*)(w + 23662592);
  float* G    = (float*)(w + 23678976);
  float* out1 = (float*)d_out;
  float* out2 = out1 + TOT;

  k_tr<<<dim3(64, 16, BB), 256, 0, stream>>>(x, xt);
  k_init<<<dim3(1281), 256, 0, stream>>>(Win, mp, pi0, Winb, mu_t, piw);
  // x1[c][m] = Winb . xt^T  (M=256, N=4096, K=1024)
  k_nt<<<dim3(2, 32, BB), 256, 0, stream>>>(Winb, xt, x1, bin,
      IN, WH, CH, 0, (size_t)WH * CH, (size_t)IN * WH, 0);
  // x1t[m][c] = xt . Winb^T (M=4096, N=256, K=1024)
  k_nt<<<dim3(32, 2, BB), 256, 0, stream>>>(xt, Winb, x1t, bin,
      WH, IN, CH, (size_t)WH * CH, 0, (size_t)WH * IN, 1);
  for (int it = 0; it < 3; ++it) {
    k_em1<<<dim3(64, BB), 256, 0, stream>>>(x1t, mu_t, piw, pmn, pt);
    k_spost<<<dim3(BB * ND), 256, 0, stream>>>(pt, sp, piw);
    k_em2<<<dim3(32, BB), 256, 0, stream>>>(x1, pt, mup);
    k_mu_red<<<dim3(256), 256, 0, stream>>>(mup, sp, mu, mu_t);
  }
  k_G<<<dim3(16, BB), 256, 0, stream>>>(pt, gp);
  k_G_reduce<<<dim3(64), 256, 0, stream>>>(gp, G);
  k_gc1<<<dim3(8, BB), 256, 0, stream>>>(mu, Wa, ba, Wd, bd, xa, dv);
  k_gc2<<<dim3(BB), 256, 0, stream>>>(xa, dv, ah);
  k_gc3<<<dim3(16, BB), 256, 0, stream>>>(mu, ah, t2);
  k_gc4<<<dim3(16, BB), 256, 0, stream>>>(t2, gw, mu, x2g);
  k_zgemm<<<dim3(16, BB), 256, 0, stream>>>(Wo2, mu, z2, zb2);
  k_zgemm<<<dim3(16, BB), 256, 0, stream>>>(Wo, x2g, z1, zb1);
  k_stats<<<dim3(256), 256, 0, stream>>>(z1, z2, sp, G, gam, bet, gam2, bet2, abc);
  k_epi<<<dim3(16, 16, BB), 256, 0, stream>>>(zb1, zb2, pmn, abc, x, out1, out2);
}

// Round 3
// 298.452 us; speedup vs baseline: 1.9873x; 1.1070x over previous
//
#include <hip/hip_runtime.h>
#include <math.h>

// ---------------------------------------------------------------------------
// Intra_graph forward, MI355X. Round 3: kernel-count collapse (22 -> 11).
//  * k_x1: single pass over x (f32) -> LDS bf16 transpose staging -> MFMA
//    against L2-resident Winb -> writes BOTH x1[c][m] and x1t[m][c]
//  * k_em: one kernel per EM iteration (lik MFMA + in-reg softmax + LDS
//    transpose + mu-partials MFMA + sp atomics + G partials on last iter)
//  * k_gc: gc1..gc4 fused, using gw@(x2@A) == (gw@x2)@A
//  * k_zdual: both z-GEMMs in one launch (blockIdx.z)
//  * big scratch (mup, gp, z1, z2) lives in d_out; ws ~21 MB
// ---------------------------------------------------------------------------

typedef unsigned short u16;
typedef short s16x8 __attribute__((ext_vector_type(8)));
typedef float f32x4 __attribute__((ext_vector_type(4)));

constexpr int BB  = 4;
constexpr int CH  = 1024;
constexpr int IN  = 256;
constexpr int ND  = 64;
constexpr int WH  = 4096;
constexpr int DCN = 128;
constexpr size_t TOT = (size_t)BB * CH * WH;

__device__ inline u16 f2bf(float f) {
  unsigned u = __float_as_uint(f);
  return (u16)((u + 0x7fffu + ((u >> 16) & 1u)) >> 16);
}
__device__ inline s16x8 ld8(const u16* p) { return *(const s16x8*)p; }
#define MFMA16(a, b, c) __builtin_amdgcn_mfma_f32_16x16x32_bf16(a, b, c, 0, 0, 0)

// ---------------- init: Winb bf16, mu_t bf16 [b][n][c], piw, zero sp -------
__global__ void k_init(const float* __restrict__ Win, const float* __restrict__ mp,
                       const float* __restrict__ pi0, u16* __restrict__ Winb,
                       u16* __restrict__ mu_t, float* __restrict__ piw,
                       float* __restrict__ sp) {
  int idx = blockIdx.x * 256 + threadIdx.x;
  if (idx < IN * CH) { Winb[idx] = f2bf(Win[idx]); return; }
  int j = idx - IN * CH;
  if (j < BB * ND * IN) {
    int bb = j >> 14, n = (j >> 8) & 63, c = j & 255;
    mu_t[((size_t)(bb * ND + n)) * IN + c] = f2bf(mp[c * ND + n]);
    return;
  }
  j -= BB * ND * IN;
  if (j < BB * ND) { piw[j] = pi0[j & 63]; return; }
  j -= BB * ND;
  if (j < 3 * BB * ND) sp[j] = 0.f;
}

// ---------------- x1 = W_in @ x + b_in, dual layout ------------------------
// grid (64 m-tiles, BB), 512 threads = 8 waves. Wave: c-tile 64 x m-half 32.
__global__ __launch_bounds__(512) void k_x1(
    const float* __restrict__ x, const u16* __restrict__ Winb,
    const float* __restrict__ bin, u16* __restrict__ x1, u16* __restrict__ x1t) {
  __shared__ u16 lt[64][40];   // [m][i], pad 40 -> 80B rows, 16B aligned
  const int t = threadIdx.x, w = t >> 6, lr = t & 15, lg = (t >> 4) & 3;
  const int wc = w & 3, wm = w >> 2;
  const int m0 = blockIdx.x * 64, b = blockIdx.y;
  const int si = t >> 4, sm = (t & 15) * 4;
  const float* xb = x + (size_t)b * CH * WH + m0 + sm;
  f32x4 acc[4][2];
#pragma unroll
  for (int i = 0; i < 4; ++i)
#pragma unroll
    for (int j = 0; j < 2; ++j) acc[i][j] = (f32x4){0.f, 0.f, 0.f, 0.f};
  const u16* wp = Winb + (size_t)(wc * 64 + lr) * CH + lg * 8;

  float4 nxt = *(const float4*)&xb[(size_t)si * WH];
  for (int k0 = 0; k0 < CH; k0 += 32) {
    float4 cur = nxt;
    __syncthreads();
    lt[sm + 0][si] = f2bf(cur.x); lt[sm + 1][si] = f2bf(cur.y);
    lt[sm + 2][si] = f2bf(cur.z); lt[sm + 3][si] = f2bf(cur.w);
    if (k0 + 32 < CH) nxt = *(const float4*)&xb[(size_t)(k0 + 32 + si) * WH];
    __syncthreads();
    s16x8 af[4], bf[2];
#pragma unroll
    for (int i = 0; i < 4; ++i) af[i] = ld8(wp + (size_t)i * 16 * CH + k0);
#pragma unroll
    for (int j = 0; j < 2; ++j) bf[j] = *(const s16x8*)&lt[wm * 32 + j * 16 + lr][lg * 8];
#pragma unroll
    for (int i = 0; i < 4; ++i)
#pragma unroll
      for (int j = 0; j < 2; ++j) acc[i][j] = MFMA16(af[i], bf[j], acc[i][j]);
  }
#pragma unroll
  for (int i = 0; i < 4; ++i) {
    const int cb = wc * 64 + i * 16 + lg * 4;
    const float4 bi = *(const float4*)&bin[cb];
    const float bia[4] = {bi.x, bi.y, bi.z, bi.w};
#pragma unroll
    for (int j = 0; j < 2; ++j) {
      const int m = m0 + wm * 32 + j * 16 + lr;
      float v[4];
#pragma unroll
      for (int r = 0; r < 4; ++r) v[r] = acc[i][j][r] + bia[r];
      ushort4 o;
      o.x = f2bf(v[0]); o.y = f2bf(v[1]); o.z = f2bf(v[2]); o.w = f2bf(v[3]);
      *(ushort4*)&x1t[((size_t)b * WH + m) * IN + cb] = o;
#pragma unroll
      for (int r = 0; r < 4; ++r)
        x1[((size_t)b * IN + cb + r) * WH + m] = f2bf(v[r]);
    }
  }
}

// ---------------- fused EM iteration ---------------------------------------
// grid (32 m-chunks of 128, BB), 512 threads = 8 waves.
// A: lik+softmax -> pmn global + ptl LDS [n][m];  sp atomics
// B: mu partials mup[ch] = x1 . ptl^T
// C (doG): G partials gp[ch] = ptl . ptl^T
__global__ __launch_bounds__(512) void k_em(
    const u16* __restrict__ x1, const u16* __restrict__ x1t,
    const u16* __restrict__ mu_t, const float* __restrict__ piw,
    float* __restrict__ sp, u16* __restrict__ pmn,
    float* __restrict__ mup, float* __restrict__ gp, int doG) {
  __shared__ u16 ptl[64][136];   // [n][m(128)] pad 136 -> 272B rows
  const int t = threadIdx.x, w = t >> 6, lr = t & 15, lg = (t >> 4) & 3;
  const int mch = blockIdx.x, b = blockIdx.y;
  // ---- phase A ----
  {
    f32x4 acc[4];
#pragma unroll
    for (int f = 0; f < 4; ++f) acc[f] = (f32x4){0.f, 0.f, 0.f, 0.f};
    const u16* ap = x1t + ((size_t)b * WH + mch * 128 + w * 16 + lr) * IN + lg * 8;
    const u16* bp = mu_t + ((size_t)b * ND + lr) * IN + lg * 8;
#pragma unroll
    for (int k0 = 0; k0 < IN; k0 += 32) {
      s16x8 a = ld8(ap + k0);
#pragma unroll
      for (int f = 0; f < 4; ++f)
        acc[f] = MFMA16(a, ld8(bp + f * 16 * IN + k0), acc[f]);
    }
    float pi_[4], spart[4] = {0.f, 0.f, 0.f, 0.f};
#pragma unroll
    for (int f = 0; f < 4; ++f) pi_[f] = piw[b * ND + f * 16 + lr];
#pragma unroll
    for (int r = 0; r < 4; ++r) {
      float v0 = acc[0][r], v1 = acc[1][r], v2 = acc[2][r], v3 = acc[3][r];
      float mx = fmaxf(fmaxf(v0, v1), fmaxf(v2, v3));
      mx = fmaxf(mx, __shfl_xor(mx, 1)); mx = fmaxf(mx, __shfl_xor(mx, 2));
      mx = fmaxf(mx, __shfl_xor(mx, 4)); mx = fmaxf(mx, __shfl_xor(mx, 8));
      float e0 = __expf(v0 - mx) * pi_[0], e1 = __expf(v1 - mx) * pi_[1];
      float e2 = __expf(v2 - mx) * pi_[2], e3 = __expf(v3 - mx) * pi_[3];
      float s = e0 + e1 + e2 + e3;
      s += __shfl_xor(s, 1); s += __shfl_xor(s, 2);
      s += __shfl_xor(s, 4); s += __shfl_xor(s, 8);
      const float inv = 1.f / (1e-18f + s);
      e0 *= inv; e1 *= inv; e2 *= inv; e3 *= inv;
      const int mloc = w * 16 + lg * 4 + r;
      const size_t gbase = ((size_t)b * WH + mch * 128 + mloc) * ND + lr;
      u16 q0 = f2bf(e0), q1 = f2bf(e1), q2 = f2bf(e2), q3 = f2bf(e3);
      pmn[gbase + 0]  = q0; pmn[gbase + 16] = q1;
      pmn[gbase + 32] = q2; pmn[gbase + 48] = q3;
      ptl[0 + lr][mloc]  = q0; ptl[16 + lr][mloc] = q1;
      ptl[32 + lr][mloc] = q2; ptl[48 + lr][mloc] = q3;
      spart[0] += e0; spart[1] += e1; spart[2] += e2; spart[3] += e3;
    }
#pragma unroll
    for (int f = 0; f < 4; ++f) {
      spart[f] += __shfl_xor(spart[f], 16);
      spart[f] += __shfl_xor(spart[f], 32);
    }
    if (((t >> 4) & 3) == 0) {
#pragma unroll
      for (int f = 0; f < 4; ++f)
        atomicAdd(&sp[b * ND + f * 16 + lr], spart[f]);
    }
  }
  __syncthreads();
  // ---- phase B ----
  {
    const int ct = (w & 3) * 64, nh = (w >> 2) * 32;
    f32x4 acc[4][2];
#pragma unroll
    for (int i = 0; i < 4; ++i)
#pragma unroll
      for (int j = 0; j < 2; ++j) acc[i][j] = (f32x4){0.f, 0.f, 0.f, 0.f};
    const u16* ap = x1 + ((size_t)b * IN + ct + lr) * WH + mch * 128 + lg * 8;
#pragma unroll
    for (int ks = 0; ks < 4; ++ks) {
      s16x8 af[4], bf[2];
#pragma unroll
      for (int i = 0; i < 4; ++i) af[i] = ld8(ap + (size_t)i * 16 * WH + ks * 32);
#pragma unroll
      for (int j = 0; j < 2; ++j)
        bf[j] = *(const s16x8*)&ptl[nh + j * 16 + lr][ks * 32 + lg * 8];
#pragma unroll
      for (int i = 0; i < 4; ++i)
#pragma unroll
        for (int j = 0; j < 2; ++j) acc[i][j] = MFMA16(af[i], bf[j], acc[i][j]);
    }
    float* mo = mup + ((size_t)mch * BB + b) * (IN * ND);
#pragma unroll
    for (int i = 0; i < 4; ++i)
#pragma unroll
      for (int j = 0; j < 2; ++j)
#pragma unroll
        for (int r = 0; r < 4; ++r) {
          const int c = ct + i * 16 + lg * 4 + r, n = nh + j * 16 + lr;
          mo[c * ND + n] = acc[i][j][r];
        }
  }
  // ---- phase C: G partials ----
  if (doG && w < 4) {
    f32x4 acc[4];
#pragma unroll
    for (int j = 0; j < 4; ++j) acc[j] = (f32x4){0.f, 0.f, 0.f, 0.f};
#pragma unroll
    for (int ks = 0; ks < 4; ++ks) {
      s16x8 a = *(const s16x8*)&ptl[w * 16 + lr][ks * 32 + lg * 8];
#pragma unroll
      for (int j = 0; j < 4; ++j) {
        s16x8 bq = *(const s16x8*)&ptl[j * 16 + lr][ks * 32 + lg * 8];
        acc[j] = MFMA16(a, bq, acc[j]);
      }
    }
    float* go = gp + ((size_t)mch * BB + b) * (ND * ND);
#pragma unroll
    for (int j = 0; j < 4; ++j)
#pragma unroll
      for (int r = 0; r < 4; ++r) {
        const int n1 = w * 16 + lg * 4 + r, n2 = j * 16 + lr;
        go[n1 * ND + n2] = acc[j][r];
      }
  }
}

// ---------------- mu reduce + normalize + piw (+ G reduce last iter) -------
__global__ void k_mu_red(const float* __restrict__ mup, const float* __restrict__ spb,
                         float* __restrict__ piw, float* __restrict__ mu,
                         u16* __restrict__ mu_t, const float* __restrict__ gp,
                         float* __restrict__ G, int doG) {
  const int idx = blockIdx.x * 256 + threadIdx.x;   // grid 256 -> 65536
  const int bb = idx >> 14, c = (idx >> 6) & 255, n = idx & 63;
  float s = 0.f;
#pragma unroll
  for (int ch = 0; ch < 32; ++ch)
    s += mup[((size_t)ch * BB + bb) * (IN * ND) + c * ND + n];
  const float v = s / (1e-18f + spb[bb * ND + n]);
  mu[idx] = v;
  mu_t[((size_t)(bb * ND + n)) * IN + c] = f2bf(v);
  if (idx < BB * ND) piw[idx] = spb[idx] * (1.f / (float)WH);
  if (doG && idx < BB * ND * ND) {
    float g = 0.f;
#pragma unroll
    for (int ch = 0; ch < 32; ++ch) g += gp[(size_t)ch * (BB * ND * ND) + idx];
    G[idx] = g;
  }
}

// ---------------- fused GC layer (gc1..gc4), one block per batch -----------
// uses gw@(x2@A) == (gw@x2)@A
__global__ __launch_bounds__(1024) void k_gc(
    const float* __restrict__ mu, const float* __restrict__ Wa,
    const float* __restrict__ ba, const float* __restrict__ Wd,
    const float* __restrict__ bd, const float* __restrict__ gw,
    float* __restrict__ x2g) {
  __shared__ float sx2[IN * ND];     // 64 KB [c][n]
  __shared__ float sA[ND * 65];      // 16.25 KB
  __shared__ float reg_[IN * ND];    // 64 KB: xa (first 8K floats) then q
  __shared__ float ssx[IN];
  __shared__ float sdv[DCN];
  __shared__ float su[ND];
  __shared__ float sdeg[ND];
  const int t = threadIdx.x, b = blockIdx.x;
  const float* src = mu + (size_t)b * IN * ND;
#pragma unroll
  for (int q4 = 0; q4 < 4; ++q4)
    *(float4*)&sx2[q4 * 4096 + t * 4] = *(const float4*)&src[q4 * 4096 + t * 4];
  __syncthreads();
  if (t < IN) {
    float s = 0.f;
    for (int n = 0; n < ND; ++n) s += sx2[t * 64 + ((n + t) & 63)];
    ssx[t] = s;
  }
  __syncthreads();
  if (t < DCN) {
    float a = 0.f;
    for (int i = 0; i < IN; ++i) a += Wd[t * IN + i] * ssx[i];
    const float xm = a * (1.f / ND) + bd[t];
    sdv[t] = 1.f / (1.f + __expf(-xm)) - 0.5f;
  }
  // xa = Wa @ x2 + ba : t -> dc = t>>3, 8 n
  {
    const int dc = t >> 3, n8 = (t & 7) * 8;
    float a0=0,a1=0,a2=0,a3=0,a4=0,a5=0,a6=0,a7=0;
    for (int i = 0; i < IN; ++i) {
      const float wv = Wa[dc * IN + i];
      const float4 v0 = *(const float4*)&sx2[i * 64 + n8];
      const float4 v1 = *(const float4*)&sx2[i * 64 + n8 + 4];
      a0 += wv * v0.x; a1 += wv * v0.y; a2 += wv * v0.z; a3 += wv * v0.w;
      a4 += wv * v1.x; a5 += wv * v1.y; a6 += wv * v1.z; a7 += wv * v1.w;
    }
    const float bav = ba[dc];
    float* xa = reg_ + dc * 64 + n8;
    xa[0]=a0+bav; xa[1]=a1+bav; xa[2]=a2+bav; xa[3]=a3+bav;
    xa[4]=a4+bav; xa[5]=a5+bav; xa[6]=a6+bav; xa[7]=a7+bav;
  }
  __syncthreads();
  if (t < ND) {
    float s = 0.f;
    for (int dc = 0; dc < DCN; ++dc) s += reg_[dc * 64 + t];
    su[t] = s;
  }
  __syncthreads();
  // A = relu(0.5 u u^T + xa^T diag(dv) xa) + I
  {
    const int n1 = t >> 4, n2q = (t & 15) * 4;
    const float u1 = su[n1];
    float c0 = 0.5f * u1 * su[n2q + 0], c1 = 0.5f * u1 * su[n2q + 1];
    float c2 = 0.5f * u1 * su[n2q + 2], c3 = 0.5f * u1 * su[n2q + 3];
    for (int dc = 0; dc < DCN; ++dc) {
      const float v = reg_[dc * 64 + n1] * sdv[dc];
      const float4 rr = *(const float4*)&reg_[dc * 64 + n2q];
      c0 += v * rr.x; c1 += v * rr.y; c2 += v * rr.z; c3 += v * rr.w;
    }
    sA[n1 * 65 + n2q + 0] = fmaxf(c0, 0.f) + (n1 == n2q + 0 ? 1.f : 0.f);
    sA[n1 * 65 + n2q + 1] = fmaxf(c1, 0.f) + (n1 == n2q + 1 ? 1.f : 0.f);
    sA[n1 * 65 + n2q + 2] = fmaxf(c2, 0.f) + (n1 == n2q + 2 ? 1.f : 0.f);
    sA[n1 * 65 + n2q + 3] = fmaxf(c3, 0.f) + (n1 == n2q + 3 ? 1.f : 0.f);
  }
  __syncthreads();
  if (t < ND) {
    float s = 0.f;
    for (int m = 0; m < ND; ++m) s += sA[m * 65 + t];
    sdeg[t] = rsqrtf(s);
  }
  __syncthreads();
  {
    const int n1 = t >> 4, n2q = (t & 15) * 4;
    const float dr = sdeg[n1];
#pragma unroll
    for (int e = 0; e < 4; ++e)
      sA[n1 * 65 + n2q + e] = dr * sA[n1 * 65 + n2q + e] * sdeg[n2q + e];
  }
  __syncthreads();
  // q = gw @ x2  (over xa region; xa dead)
  {
    const int o = t >> 2, kq = (t & 3) * 16;
    float a[16];
#pragma unroll
    for (int e = 0; e < 16; ++e) a[e] = 0.f;
    for (int i = 0; i < IN; ++i) {
      const float wv = gw[(size_t)o * IN + i];
      const float* row = &sx2[i * 64 + kq];
#pragma unroll
      for (int e = 0; e < 16; ++e) a[e] += wv * row[e];
    }
    __syncthreads();
    float* qd = reg_ + o * 64 + kq;
#pragma unroll
    for (int e = 0; e < 16; ++e) qd[e] = a[e];
  }
  __syncthreads();
  // x2g = relu(q @ Ahat) + x2
  {
    const int o = t >> 2, nq = (t & 3) * 16;
    float a[16];
#pragma unroll
    for (int e = 0; e < 16; ++e) a[e] = 0.f;
    for (int k = 0; k < ND; ++k) {
      const float qq = reg_[o * 64 + k];
      const float* row = &sA[k * 65 + nq];
#pragma unroll
      for (int e = 0; e < 16; ++e) a[e] += qq * row[e];
    }
    float* dst = x2g + (size_t)b * IN * ND + o * 64 + nq;
    const float* xv = &sx2[o * 64 + nq];
#pragma unroll
    for (int e = 0; e < 16; ++e) dst[e] = fmaxf(a[e], 0.f) + xv[e];
  }
}

// ---------------- dual z-GEMM: z = W @ v (f32) + zb bf16 -------------------
__global__ __launch_bounds__(256) void k_zdual(
    const float* __restrict__ Wo, const float* __restrict__ v1,
    float* __restrict__ z1o, u16* __restrict__ zb1o,
    const float* __restrict__ Wo2, const float* __restrict__ v2,
    float* __restrict__ z2o, u16* __restrict__ zb2o) {
  const float* W = blockIdx.z ? Wo2 : Wo;
  const float* v = blockIdx.z ? v2 : v1;
  float* z  = blockIdx.z ? z2o : z1o;
  u16* zb   = blockIdx.z ? zb2o : zb1o;
  __shared__ float As[16][68];
  __shared__ float Bs[16][64];
  const int t = threadIdx.x, tx = t & 15, ty = t >> 4;
  const int o0 = blockIdx.x * 64, bb = blockIdx.y;
  const int aoo = t >> 2, akq = (t & 3) * 4;
  const int bkk = t >> 4, bnq = (t & 15) * 4;
  float acc[4][4] = {};
  for (int k0 = 0; k0 < IN; k0 += 16) {
    {
      float4 w4 = *(const float4*)&W[(size_t)(o0 + aoo) * IN + k0 + akq];
      As[akq + 0][aoo] = w4.x; As[akq + 1][aoo] = w4.y;
      As[akq + 2][aoo] = w4.z; As[akq + 3][aoo] = w4.w;
    }
    *(float4*)&Bs[bkk][bnq] = *(const float4*)&v[((size_t)bb * IN + k0 + bkk) * ND + bnq];
    __syncthreads();
#pragma unroll
    for (int kk = 0; kk < 16; ++kk) {
      float4 a4 = *(const float4*)&As[kk][ty * 4];
      float4 b4 = *(const float4*)&Bs[kk][tx * 4];
      float ar[4] = {a4.x, a4.y, a4.z, a4.w}, br[4] = {b4.x, b4.y, b4.z, b4.w};
#pragma unroll
      for (int i = 0; i < 4; ++i)
#pragma unroll
        for (int j = 0; j < 4; ++j) acc[i][j] += ar[i] * br[j];
    }
    __syncthreads();
  }
#pragma unroll
  for (int i = 0; i < 4; ++i) {
    float4 r = make_float4(acc[i][0], acc[i][1], acc[i][2], acc[i][3]);
    const size_t off = ((size_t)bb * CH + o0 + ty * 4 + i) * ND + tx * 4;
    *(float4*)&z[off] = r;
    ushort4 h;
    h.x = f2bf(r.x); h.y = f2bf(r.y); h.z = f2bf(r.z); h.w = f2bf(r.w);
    *(ushort4*)&zb[off] = h;
  }
}

// ---------------- BN stats -------------------------------------------------
__global__ __launch_bounds__(256) void k_stats(
    const float* __restrict__ z1, const float* __restrict__ z2,
    const float* __restrict__ sp, const float* __restrict__ G,
    const float* __restrict__ gam, const float* __restrict__ bet,
    const float* __restrict__ gam2, const float* __restrict__ bet2,
    float* __restrict__ abc) {
  const int t = threadIdx.x;
  const int o = blockIdx.x * 4 + (t >> 6), lane = t & 63;
#pragma unroll
  for (int br = 0; br < 2; ++br) {
    const float* z = br ? z2 : z1;
    float macc = 0.f, eacc = 0.f;
    for (int bb = 0; bb < BB; ++bb) {
      const float zv = z[((size_t)bb * CH + o) * ND + lane];
      float s1 = zv * sp[bb * ND + lane];
      const float* Gb = G + (size_t)bb * ND * ND;
      float gz = 0.f;
      for (int k = 0; k < ND; ++k) {
        const float zk = __shfl(zv, k);
        gz += Gb[k * ND + lane] * zk;
      }
      float q = zv * gz;
#pragma unroll
      for (int off = 32; off; off >>= 1) {
        s1 += __shfl_xor(s1, off);
        q  += __shfl_xor(q, off);
      }
      macc += s1; eacc += q;
    }
    const float inv = 1.f / (float)((size_t)BB * WH);
    const float mean = macc * inv;
    const float var  = eacc * inv - mean * mean;
    const float a = (br ? gam2[o] : gam[o]) * rsqrtf(var + 1e-5f);
    const float c = (br ? bet2[o] : bet[o]) - mean * a;
    if (lane == 0) { abc[br * 2 * CH + o] = a; abc[br * 2 * CH + CH + o] = c; }
  }
}

// ---------------- epilogue: MFMA y=z.post^T, BN, residual relus ------------
__global__ __launch_bounds__(256) void k_epi(
    const u16* __restrict__ zb1, const u16* __restrict__ zb2,
    const u16* __restrict__ post, const float* __restrict__ abc,
    const float* __restrict__ x, float* __restrict__ out1, float* __restrict__ out2) {
  const int t = threadIdx.x, w = t >> 6, lr = t & 15, lg = (t >> 4) & 3;
  const int m0 = blockIdx.x * 256 + w * 64, o0 = blockIdx.y * 64, bb = blockIdx.z;
  f32x4 acc1[4][4], acc2[4][4];
#pragma unroll
  for (int i = 0; i < 4; ++i)
#pragma unroll
    for (int j = 0; j < 4; ++j) {
      acc1[i][j] = (f32x4){0.f, 0.f, 0.f, 0.f};
      acc2[i][j] = (f32x4){0.f, 0.f, 0.f, 0.f};
    }
  const u16* z1p = zb1 + ((size_t)bb * CH + o0 + lr) * ND + lg * 8;
  const u16* z2p = zb2 + ((size_t)bb * CH + o0 + lr) * ND + lg * 8;
  const u16* pp  = post + ((size_t)bb * WH + m0 + lr) * ND + lg * 8;
#pragma unroll
  for (int ks = 0; ks < 2; ++ks) {
    s16x8 a1[4], a2[4], bq[4];
#pragma unroll
    for (int i = 0; i < 4; ++i) {
      a1[i] = ld8(z1p + i * 16 * ND + ks * 32);
      a2[i] = ld8(z2p + i * 16 * ND + ks * 32);
    }
#pragma unroll
    for (int j = 0; j < 4; ++j) bq[j] = ld8(pp + j * 16 * ND + ks * 32);
#pragma unroll
    for (int i = 0; i < 4; ++i)
#pragma unroll
      for (int j = 0; j < 4; ++j) {
        acc1[i][j] = MFMA16(a1[i], bq[j], acc1[i][j]);
        acc2[i][j] = MFMA16(a2[i], bq[j], acc2[i][j]);
      }
  }
#pragma unroll
  for (int i = 0; i < 4; ++i)
#pragma unroll
    for (int r = 0; r < 4; ++r) {
      const int o = o0 + i * 16 + lg * 4 + r;
      const float a1v = abc[o], c1v = abc[CH + o];
      const float a2v = abc[2 * CH + o], c2v = abc[3 * CH + o];
      const size_t base = ((size_t)bb * CH + o) * WH + m0 + lr;
#pragma unroll
      for (int j = 0; j < 4; ++j) {
        const size_t off = base + j * 16;
        const float xv = x[off];
        out1[off] = fmaxf(fmaxf(a1v * acc1[i][j][r] + c1v, 0.f) + xv, 0.f);
        out2[off] = fmaxf(fmaxf(a2v * acc2[i][j][r] + c2v, 0.f) + xv, 0.f);
      }
    }
}

// ---------------------------------------------------------------------------
extern "C" void kernel_launch(void* const* d_in, const int* in_sizes, int n_in,
                              void* d_out, int out_size, void* d_ws, size_t ws_size,
                              hipStream_t stream) {
  (void)in_sizes; (void)n_in; (void)out_size; (void)ws_size;
  const float* x    = (const float*)d_in[0];
  const float* Win  = (const float*)d_in[1];
  const float* bin  = (const float*)d_in[2];
  const float* mp   = (const float*)d_in[3];
  const float* pi0  = (const float*)d_in[4];
  const float* Wa   = (const float*)d_in[5];
  const float* ba   = (const float*)d_in[6];
  const float* Wd   = (const float*)d_in[7];
  const float* bd   = (const float*)d_in[8];
  const float* gw   = (const float*)d_in[9];
  const float* Wo   = (const float*)d_in[10];
  const float* gam  = (const float*)d_in[12];
  const float* bet  = (const float*)d_in[13];
  const float* Wo2  = (const float*)d_in[14];
  const float* gam2 = (const float*)d_in[16];
  const float* bet2 = (const float*)d_in[17];

  char* ob = (char*)d_out;
  char* wp = (char*)d_ws;
  // scratch in d_out (dead before k_epi writes outputs):
  float* mup = (float*)(ob + 0);          // 8.4 MB (32 chunks x 4 b x 16384)
  float* gp  = (float*)(ob + 8388608);    // 2 MB
  float* z1  = (float*)(ob + 10485760);   // 1 MB
  float* z2  = (float*)(ob + 11534336);   // 1 MB
  // ws (~21.2 MB):
  u16*   x1   = (u16*)(wp + 0);           // 8.4 MB [b][c][m]
  u16*   x1t  = (u16*)(wp + 8388608);     // 8.4 MB [b][m][c]
  u16*   Winb = (u16*)(wp + 16777216);    // 0.5 MB
  u16*   mu_t = (u16*)(wp + 17301504);    // 128 KB [b][n][c]
  u16*   pmn  = (u16*)(wp + 17432576);    // 2 MB [b][m][n]
  float* mu   = (float*)(wp + 19529728);  // 256 KB [b][c][n]
  float* x2g  = (float*)(wp + 19791872);  // 256 KB
  u16*   zb1  = (u16*)(wp + 20054016);    // 0.5 MB
  u16*   zb2  = (u16*)(wp + 20578304);    // 0.5 MB
  float* sp3  = (float*)(wp + 21102592);  // 3 KB (3 buffers x 256)
  float* piw  = (float*)(wp + 21105664);  // 1 KB
  float* abc  = (float*)(wp + 21106688);  // 16 KB
  float* G    = (float*)(wp + 21123072);  // 64 KB
  float* out1 = (float*)d_out;
  float* out2 = out1 + TOT;

  k_init<<<dim3(1284), 256, 0, stream>>>(Win, mp, pi0, Winb, mu_t, piw, sp3);
  k_x1<<<dim3(64, BB), 512, 0, stream>>>(x, Winb, bin, x1, x1t);
  for (int it = 0; it < 3; ++it) {
    float* spb = sp3 + it * 256;
    const int doG = (it == 2);
    k_em<<<dim3(32, BB), 512, 0, stream>>>(x1, x1t, mu_t, piw, spb, pmn, mup, gp, doG);
    k_mu_red<<<dim3(256), 256, 0, stream>>>(mup, spb, piw, mu, mu_t, gp, G, doG);
  }
  k_gc<<<dim3(BB), 1024, 0, stream>>>(mu, Wa, ba, Wd, bd, gw, x2g);
  k_zdual<<<dim3(16, BB, 2), 256, 0, stream>>>(Wo, x2g, z1, zb1, Wo2, mu, z2, zb2);
  k_stats<<<dim3(256), 256, 0, stream>>>(z1, z2, sp3 + 512, G, gam, bet, gam2, bet2, abc);
  k_epi<<<dim3(16, 16, BB), 256, 0, stream>>>(zb1, zb2, pmn, abc, x, out1, out2);
}

// Round 4
// 232.902 us; speedup vs baseline: 2.5467x; 1.2814x over previous
//
#include <hip/hip_runtime.h>
#include <math.h>

// ---------------------------------------------------------------------------
// Intra_graph forward, MI355X. Round 4: fix the two occupancy holes R3 found.
//  * k_gc (95us @ 0.65% occupancy) -> k_gcA (28 blk, vectorized weight GEMMs:
//    q=gw@x2, xa=Wa@x2+ba, dv) + k_gcB (4 blk, serial chain u->A->deg->Ahat)
//    + k_gcC (16 blk, x2g = relu(q@Ahat)+x2)
//  * k_em: 128 -> 256 blocks (m-chunk 64, 256 threads), mup/gp chunks 32->64
//  * everything else retained from R3
// ---------------------------------------------------------------------------

typedef unsigned short u16;
typedef short s16x8 __attribute__((ext_vector_type(8)));
typedef float f32x4 __attribute__((ext_vector_type(4)));

constexpr int BB  = 4;
constexpr int CH  = 1024;
constexpr int IN  = 256;
constexpr int ND  = 64;
constexpr int WH  = 4096;
constexpr int DCN = 128;
constexpr size_t TOT = (size_t)BB * CH * WH;

__device__ inline u16 f2bf(float f) {
  unsigned u = __float_as_uint(f);
  return (u16)((u + 0x7fffu + ((u >> 16) & 1u)) >> 16);
}
__device__ inline s16x8 ld8(const u16* p) { return *(const s16x8*)p; }
#define MFMA16(a, b, c) __builtin_amdgcn_mfma_f32_16x16x32_bf16(a, b, c, 0, 0, 0)

// ---------------- init: Winb bf16, mu_t bf16 [b][n][c], piw, zero sp -------
__global__ void k_init(const float* __restrict__ Win, const float* __restrict__ mp,
                       const float* __restrict__ pi0, u16* __restrict__ Winb,
                       u16* __restrict__ mu_t, float* __restrict__ piw,
                       float* __restrict__ sp) {
  int idx = blockIdx.x * 256 + threadIdx.x;
  if (idx < IN * CH) { Winb[idx] = f2bf(Win[idx]); return; }
  int j = idx - IN * CH;
  if (j < BB * ND * IN) {
    int bb = j >> 14, n = (j >> 8) & 63, c = j & 255;
    mu_t[((size_t)(bb * ND + n)) * IN + c] = f2bf(mp[c * ND + n]);
    return;
  }
  j -= BB * ND * IN;
  if (j < BB * ND) { piw[j] = pi0[j & 63]; return; }
  j -= BB * ND;
  if (j < 3 * BB * ND) sp[j] = 0.f;
}

// ---------------- x1 = W_in @ x + b_in, dual layout ------------------------
// grid (64 m-tiles, BB), 512 threads = 8 waves. Wave: c-tile 64 x m-half 32.
__global__ __launch_bounds__(512) void k_x1(
    const float* __restrict__ x, const u16* __restrict__ Winb,
    const float* __restrict__ bin, u16* __restrict__ x1, u16* __restrict__ x1t) {
  __shared__ u16 lt[64][40];
  const int t = threadIdx.x, w = t >> 6, lr = t & 15, lg = (t >> 4) & 3;
  const int wc = w & 3, wm = w >> 2;
  const int m0 = blockIdx.x * 64, b = blockIdx.y;
  const int si = t >> 4, sm = (t & 15) * 4;
  const float* xb = x + (size_t)b * CH * WH + m0 + sm;
  f32x4 acc[4][2];
#pragma unroll
  for (int i = 0; i < 4; ++i)
#pragma unroll
    for (int j = 0; j < 2; ++j) acc[i][j] = (f32x4){0.f, 0.f, 0.f, 0.f};
  const u16* wp = Winb + (size_t)(wc * 64 + lr) * CH + lg * 8;

  float4 nxt = *(const float4*)&xb[(size_t)si * WH];
  for (int k0 = 0; k0 < CH; k0 += 32) {
    float4 cur = nxt;
    __syncthreads();
    lt[sm + 0][si] = f2bf(cur.x); lt[sm + 1][si] = f2bf(cur.y);
    lt[sm + 2][si] = f2bf(cur.z); lt[sm + 3][si] = f2bf(cur.w);
    if (k0 + 32 < CH) nxt = *(const float4*)&xb[(size_t)(k0 + 32 + si) * WH];
    __syncthreads();
    s16x8 af[4], bf[2];
#pragma unroll
    for (int i = 0; i < 4; ++i) af[i] = ld8(wp + (size_t)i * 16 * CH + k0);
#pragma unroll
    for (int j = 0; j < 2; ++j) bf[j] = *(const s16x8*)&lt[wm * 32 + j * 16 + lr][lg * 8];
#pragma unroll
    for (int i = 0; i < 4; ++i)
#pragma unroll
      for (int j = 0; j < 2; ++j) acc[i][j] = MFMA16(af[i], bf[j], acc[i][j]);
  }
#pragma unroll
  for (int i = 0; i < 4; ++i) {
    const int cb = wc * 64 + i * 16 + lg * 4;
    const float4 bi = *(const float4*)&bin[cb];
    const float bia[4] = {bi.x, bi.y, bi.z, bi.w};
#pragma unroll
    for (int j = 0; j < 2; ++j) {
      const int m = m0 + wm * 32 + j * 16 + lr;
      float v[4];
#pragma unroll
      for (int r = 0; r < 4; ++r) v[r] = acc[i][j][r] + bia[r];
      ushort4 o;
      o.x = f2bf(v[0]); o.y = f2bf(v[1]); o.z = f2bf(v[2]); o.w = f2bf(v[3]);
      *(ushort4*)&x1t[((size_t)b * WH + m) * IN + cb] = o;
#pragma unroll
      for (int r = 0; r < 4; ++r)
        x1[((size_t)b * IN + cb + r) * WH + m] = f2bf(v[r]);
    }
  }
}

// ---------------- fused EM iteration ---------------------------------------
// grid (64 m-chunks of 64, BB), 256 threads = 4 waves.
__global__ __launch_bounds__(256) void k_em(
    const u16* __restrict__ x1, const u16* __restrict__ x1t,
    const u16* __restrict__ mu_t, const float* __restrict__ piw,
    float* __restrict__ sp, u16* __restrict__ pmn,
    float* __restrict__ mup, float* __restrict__ gp, int doG) {
  __shared__ u16 ptl[64][72];   // [n][m(64)] pad -> 144B rows
  const int t = threadIdx.x, w = t >> 6, lr = t & 15, lg = (t >> 4) & 3;
  const int mch = blockIdx.x, b = blockIdx.y;
  // ---- phase A: lik + softmax ----
  {
    f32x4 acc[4];
#pragma unroll
    for (int f = 0; f < 4; ++f) acc[f] = (f32x4){0.f, 0.f, 0.f, 0.f};
    const u16* ap = x1t + ((size_t)b * WH + mch * 64 + w * 16 + lr) * IN + lg * 8;
    const u16* bp = mu_t + ((size_t)b * ND + lr) * IN + lg * 8;
#pragma unroll
    for (int k0 = 0; k0 < IN; k0 += 32) {
      s16x8 a = ld8(ap + k0);
#pragma unroll
      for (int f = 0; f < 4; ++f)
        acc[f] = MFMA16(a, ld8(bp + f * 16 * IN + k0), acc[f]);
    }
    float pi_[4], spart[4] = {0.f, 0.f, 0.f, 0.f};
#pragma unroll
    for (int f = 0; f < 4; ++f) pi_[f] = piw[b * ND + f * 16 + lr];
#pragma unroll
    for (int r = 0; r < 4; ++r) {
      float v0 = acc[0][r], v1 = acc[1][r], v2 = acc[2][r], v3 = acc[3][r];
      float mx = fmaxf(fmaxf(v0, v1), fmaxf(v2, v3));
      mx = fmaxf(mx, __shfl_xor(mx, 1)); mx = fmaxf(mx, __shfl_xor(mx, 2));
      mx = fmaxf(mx, __shfl_xor(mx, 4)); mx = fmaxf(mx, __shfl_xor(mx, 8));
      float e0 = __expf(v0 - mx) * pi_[0], e1 = __expf(v1 - mx) * pi_[1];
      float e2 = __expf(v2 - mx) * pi_[2], e3 = __expf(v3 - mx) * pi_[3];
      float s = e0 + e1 + e2 + e3;
      s += __shfl_xor(s, 1); s += __shfl_xor(s, 2);
      s += __shfl_xor(s, 4); s += __shfl_xor(s, 8);
      const float inv = 1.f / (1e-18f + s);
      e0 *= inv; e1 *= inv; e2 *= inv; e3 *= inv;
      const int mloc = w * 16 + lg * 4 + r;
      const size_t gbase = ((size_t)b * WH + mch * 64 + mloc) * ND + lr;
      u16 q0 = f2bf(e0), q1 = f2bf(e1), q2 = f2bf(e2), q3 = f2bf(e3);
      pmn[gbase + 0]  = q0; pmn[gbase + 16] = q1;
      pmn[gbase + 32] = q2; pmn[gbase + 48] = q3;
      ptl[0 + lr][mloc]  = q0; ptl[16 + lr][mloc] = q1;
      ptl[32 + lr][mloc] = q2; ptl[48 + lr][mloc] = q3;
      spart[0] += e0; spart[1] += e1; spart[2] += e2; spart[3] += e3;
    }
#pragma unroll
    for (int f = 0; f < 4; ++f) {
      spart[f] += __shfl_xor(spart[f], 16);
      spart[f] += __shfl_xor(spart[f], 32);
    }
    if (((t >> 4) & 3) == 0) {
#pragma unroll
      for (int f = 0; f < 4; ++f)
        atomicAdd(&sp[b * ND + f * 16 + lr], spart[f]);
    }
  }
  __syncthreads();
  // ---- phase B: mu partials, wave w = c-tile w*64, K = 64 ----
  {
    f32x4 acc[4][4];
#pragma unroll
    for (int i = 0; i < 4; ++i)
#pragma unroll
      for (int j = 0; j < 4; ++j) acc[i][j] = (f32x4){0.f, 0.f, 0.f, 0.f};
    const u16* ap = x1 + ((size_t)b * IN + w * 64 + lr) * WH + mch * 64 + lg * 8;
#pragma unroll
    for (int ks = 0; ks < 2; ++ks) {
      s16x8 af[4], bf[4];
#pragma unroll
      for (int i = 0; i < 4; ++i) af[i] = ld8(ap + (size_t)i * 16 * WH + ks * 32);
#pragma unroll
      for (int j = 0; j < 4; ++j)
        bf[j] = *(const s16x8*)&ptl[j * 16 + lr][ks * 32 + lg * 8];
#pragma unroll
      for (int i = 0; i < 4; ++i)
#pragma unroll
        for (int j = 0; j < 4; ++j) acc[i][j] = MFMA16(af[i], bf[j], acc[i][j]);
    }
    float* mo = mup + ((size_t)mch * BB + b) * (IN * ND);
#pragma unroll
    for (int i = 0; i < 4; ++i)
#pragma unroll
      for (int j = 0; j < 4; ++j)
#pragma unroll
        for (int r = 0; r < 4; ++r) {
          const int c = w * 64 + i * 16 + lg * 4 + r, n = j * 16 + lr;
          mo[c * ND + n] = acc[i][j][r];
        }
  }
  // ---- phase C: G partials (last iter) ----
  if (doG) {
    f32x4 acc[4];
#pragma unroll
    for (int j = 0; j < 4; ++j) acc[j] = (f32x4){0.f, 0.f, 0.f, 0.f};
#pragma unroll
    for (int ks = 0; ks < 2; ++ks) {
      s16x8 a = *(const s16x8*)&ptl[w * 16 + lr][ks * 32 + lg * 8];
#pragma unroll
      for (int j = 0; j < 4; ++j) {
        s16x8 bq = *(const s16x8*)&ptl[j * 16 + lr][ks * 32 + lg * 8];
        acc[j] = MFMA16(a, bq, acc[j]);
      }
    }
    float* go = gp + ((size_t)mch * BB + b) * (ND * ND);
#pragma unroll
    for (int j = 0; j < 4; ++j)
#pragma unroll
      for (int r = 0; r < 4; ++r) {
        const int n1 = w * 16 + lg * 4 + r, n2 = j * 16 + lr;
        go[n1 * ND + n2] = acc[j][r];
      }
  }
}

// ---------------- mu reduce + normalize + piw (+ G reduce last iter) -------
__global__ void k_mu_red(const float* __restrict__ mup, const float* __restrict__ spb,
                         float* __restrict__ piw, float* __restrict__ mu,
                         u16* __restrict__ mu_t, const float* __restrict__ gp,
                         float* __restrict__ G, int doG) {
  const int idx = blockIdx.x * 256 + threadIdx.x;   // grid 256 -> 65536
  const int bb = idx >> 14, c = (idx >> 6) & 255, n = idx & 63;
  float s = 0.f;
#pragma unroll 8
  for (int ch = 0; ch < 64; ++ch)
    s += mup[((size_t)ch * BB + bb) * (IN * ND) + (idx & 16383)];
  const float v = s / (1e-18f + spb[bb * ND + n]);
  mu[idx] = v;
  mu_t[((size_t)(bb * ND + n)) * IN + c] = f2bf(v);
  if (idx < BB * ND) piw[idx] = spb[idx] * (1.f / (float)WH);
  if (doG && idx < BB * ND * ND) {
    float g = 0.f;
#pragma unroll 8
    for (int ch = 0; ch < 64; ++ch) g += gp[(size_t)ch * (BB * ND * ND) + idx];
    G[idx] = g;
  }
}

// ---------------- GC-A: q = gw@x2, xa = Wa@x2+ba, dv -----------------------
// grid (7, BB), 256 threads. blk 0-3: q rows; 4-5: xa rows; 6: rowmean+dv.
__global__ __launch_bounds__(256) void k_gcA(
    const float* __restrict__ mu, const float* __restrict__ gw,
    const float* __restrict__ Wa, const float* __restrict__ ba,
    const float* __restrict__ Wd, const float* __restrict__ bd,
    float* __restrict__ qbuf, float* __restrict__ xabuf, float* __restrict__ dv) {
  __shared__ float sx2[IN * ND];
  __shared__ float srm[IN];
  const int t = threadIdx.x, blk = blockIdx.x, b = blockIdx.y;
  if (blk < 6) {
    const float* src = mu + (size_t)b * IN * ND;
#pragma unroll
    for (int q4 = 0; q4 < 16; ++q4)
      *(float4*)&sx2[q4 * 1024 + t * 4] = *(const float4*)&src[q4 * 1024 + t * 4];
    __syncthreads();
    const int rg = t >> 4, cg = t & 15;
    const float* W = (blk < 4) ? gw + (size_t)(blk * 64 + rg * 4) * IN
                               : Wa + (size_t)((blk - 4) * 64 + rg * 4) * IN;
    float acc[4][4] = {};
    for (int i4 = 0; i4 < 64; ++i4) {
      float4 xv[4];
#pragma unroll
      for (int e = 0; e < 4; ++e)
        xv[e] = *(const float4*)&sx2[(i4 * 4 + e) * 64 + cg * 4];
#pragma unroll
      for (int rr = 0; rr < 4; ++rr) {
        const float4 w4 = *(const float4*)&W[(size_t)rr * IN + i4 * 4];
        acc[rr][0] += w4.x * xv[0].x + w4.y * xv[1].x + w4.z * xv[2].x + w4.w * xv[3].x;
        acc[rr][1] += w4.x * xv[0].y + w4.y * xv[1].y + w4.z * xv[2].y + w4.w * xv[3].y;
        acc[rr][2] += w4.x * xv[0].z + w4.y * xv[1].z + w4.z * xv[2].z + w4.w * xv[3].z;
        acc[rr][3] += w4.x * xv[0].w + w4.y * xv[1].w + w4.z * xv[2].w + w4.w * xv[3].w;
      }
    }
    if (blk < 4) {
      float* dst = qbuf + (size_t)b * IN * ND + (size_t)(blk * 64 + rg * 4) * ND + cg * 4;
#pragma unroll
      for (int rr = 0; rr < 4; ++rr)
        *(float4*)&dst[(size_t)rr * ND] =
            make_float4(acc[rr][0], acc[rr][1], acc[rr][2], acc[rr][3]);
    } else {
      const int xr = (blk - 4) * 64 + rg * 4;
      float* dst = xabuf + (size_t)b * DCN * ND + (size_t)xr * ND + cg * 4;
#pragma unroll
      for (int rr = 0; rr < 4; ++rr) {
        const float bv = ba[xr + rr];
        *(float4*)&dst[(size_t)rr * ND] =
            make_float4(acc[rr][0] + bv, acc[rr][1] + bv, acc[rr][2] + bv, acc[rr][3] + bv);
      }
    }
  } else {
    {
      const float* row = mu + (size_t)b * IN * ND + (size_t)t * ND;
      float s = 0.f;
#pragma unroll
      for (int n4 = 0; n4 < 16; ++n4) {
        float4 v = *(const float4*)&row[n4 * 4];
        s += v.x + v.y + v.z + v.w;
      }
      srm[t] = s * (1.f / ND);
    }
    __syncthreads();
    if (t < DCN) {
      float a = 0.f;
#pragma unroll
      for (int i4 = 0; i4 < 64; ++i4) {
        float4 w4 = *(const float4*)&Wd[(size_t)t * IN + i4 * 4];
        float4 r4 = *(const float4*)&srm[i4 * 4];
        a += w4.x * r4.x + w4.y * r4.y + w4.z * r4.z + w4.w * r4.w;
      }
      a += bd[t];
      dv[b * DCN + t] = 1.f / (1.f + __expf(-a)) - 0.5f;
    }
  }
}

// ---------------- GC-B: u -> A -> deg -> Ahat ------------------------------
// grid (BB), 256 threads.
__global__ __launch_bounds__(256) void k_gcB(
    const float* __restrict__ xabuf, const float* __restrict__ dv,
    float* __restrict__ ahat) {
  __shared__ float sxa[DCN * ND];
  __shared__ float sdv[DCN];
  __shared__ float su[ND];
  __shared__ float sdeg[ND];
  __shared__ float sA[ND * 65];
  const int t = threadIdx.x, b = blockIdx.x;
  const float* src = xabuf + (size_t)b * DCN * ND;
#pragma unroll
  for (int q4 = 0; q4 < 8; ++q4)
    *(float4*)&sxa[q4 * 1024 + t * 4] = *(const float4*)&src[q4 * 1024 + t * 4];
  if (t < DCN) sdv[t] = dv[b * DCN + t];
  __syncthreads();
  if (t < ND) {
    float s = 0.f;
    for (int dc = 0; dc < DCN; ++dc) s += sxa[dc * ND + t];
    su[t] = s;
  }
  __syncthreads();
  {
    const int n1g = t >> 4, n2g = t & 15;
    float acc[4][4] = {};
    for (int dc = 0; dc < DCN; ++dc) {
      const float dvv = sdv[dc];
      float4 v1 = *(const float4*)&sxa[dc * ND + n1g * 4];
      const float4 v2 = *(const float4*)&sxa[dc * ND + n2g * 4];
      v1.x *= dvv; v1.y *= dvv; v1.z *= dvv; v1.w *= dvv;
      acc[0][0] += v1.x * v2.x; acc[0][1] += v1.x * v2.y;
      acc[0][2] += v1.x * v2.z; acc[0][3] += v1.x * v2.w;
      acc[1][0] += v1.y * v2.x; acc[1][1] += v1.y * v2.y;
      acc[1][2] += v1.y * v2.z; acc[1][3] += v1.y * v2.w;
      acc[2][0] += v1.z * v2.x; acc[2][1] += v1.z * v2.y;
      acc[2][2] += v1.z * v2.z; acc[2][3] += v1.z * v2.w;
      acc[3][0] += v1.w * v2.x; acc[3][1] += v1.w * v2.y;
      acc[3][2] += v1.w * v2.z; acc[3][3] += v1.w * v2.w;
    }
#pragma unroll
    for (int i = 0; i < 4; ++i) {
      const int n1 = n1g * 4 + i;
      const float u1 = su[n1];
#pragma unroll
      for (int j = 0; j < 4; ++j) {
        const int n2 = n2g * 4 + j;
        const float v = acc[i][j] + 0.5f * u1 * su[n2];
        sA[n1 * 65 + n2] = fmaxf(v, 0.f) + (n1 == n2 ? 1.f : 0.f);
      }
    }
  }
  __syncthreads();
  if (t < ND) {
    float s = 0.f;
    for (int m = 0; m < ND; ++m) s += sA[m * 65 + t];
    sdeg[t] = rsqrtf(s);
  }
  __syncthreads();
  {
    const int n1g = t >> 4, n2g = t & 15;
#pragma unroll
    for (int i = 0; i < 4; ++i) {
      const int n1 = n1g * 4 + i;
      const float dr = sdeg[n1];
      float4 o;
      o.x = dr * sA[n1 * 65 + n2g * 4 + 0] * sdeg[n2g * 4 + 0];
      o.y = dr * sA[n1 * 65 + n2g * 4 + 1] * sdeg[n2g * 4 + 1];
      o.z = dr * sA[n1 * 65 + n2g * 4 + 2] * sdeg[n2g * 4 + 2];
      o.w = dr * sA[n1 * 65 + n2g * 4 + 3] * sdeg[n2g * 4 + 3];
      *(float4*)&ahat[(size_t)b * ND * ND + n1 * ND + n2g * 4] = o;
    }
  }
}

// ---------------- GC-C: x2g = relu(q @ Ahat) + x2 --------------------------
// grid (4, BB), 256 threads; block: 64 rows.
__global__ __launch_bounds__(256) void k_gcC(
    const float* __restrict__ qbuf, const float* __restrict__ ahat,
    const float* __restrict__ mu, float* __restrict__ x2g) {
  __shared__ float sq[64 * 68];
  __shared__ float sAh[64 * 65];
  const int t = threadIdx.x, ro = blockIdx.x * 64, b = blockIdx.y;
  {
    const int r = t >> 2, seg = (t & 3) * 16;
    const float* qs = qbuf + (size_t)b * IN * ND + (size_t)(ro + r) * ND + seg;
#pragma unroll
    for (int f = 0; f < 4; ++f) {
      float4 v = *(const float4*)&qs[f * 4];
      sq[r * 68 + seg + f * 4 + 0] = v.x; sq[r * 68 + seg + f * 4 + 1] = v.y;
      sq[r * 68 + seg + f * 4 + 2] = v.z; sq[r * 68 + seg + f * 4 + 3] = v.w;
    }
    const float* as = ahat + (size_t)b * ND * ND + (size_t)r * ND + seg;
#pragma unroll
    for (int f = 0; f < 4; ++f) {
      float4 v = *(const float4*)&as[f * 4];
      sAh[r * 65 + seg + f * 4 + 0] = v.x; sAh[r * 65 + seg + f * 4 + 1] = v.y;
      sAh[r * 65 + seg + f * 4 + 2] = v.z; sAh[r * 65 + seg + f * 4 + 3] = v.w;
    }
  }
  __syncthreads();
  const int rg = t >> 4, cg = t & 15;
  float acc[4][4] = {};
  for (int k = 0; k < ND; ++k) {
    const float4 a4 = *(const float4*)&sAh[k * 65 + cg * 4];
    float qv[4];
#pragma unroll
    for (int rr = 0; rr < 4; ++rr) qv[rr] = sq[(rg * 4 + rr) * 68 + k];
#pragma unroll
    for (int rr = 0; rr < 4; ++rr) {
      acc[rr][0] += qv[rr] * a4.x; acc[rr][1] += qv[rr] * a4.y;
      acc[rr][2] += qv[rr] * a4.z; acc[rr][3] += qv[rr] * a4.w;
    }
  }
#pragma unroll
  for (int rr = 0; rr < 4; ++rr) {
    const size_t off = (size_t)b * IN * ND + (size_t)(ro + rg * 4 + rr) * ND + cg * 4;
    const float4 xv = *(const float4*)&mu[off];
    float4 o;
    o.x = fmaxf(acc[rr][0], 0.f) + xv.x; o.y = fmaxf(acc[rr][1], 0.f) + xv.y;
    o.z = fmaxf(acc[rr][2], 0.f) + xv.z; o.w = fmaxf(acc[rr][3], 0.f) + xv.w;
    *(float4*)&x2g[off] = o;
  }
}

// ---------------- dual z-GEMM: z = W @ v (f32) + zb bf16 -------------------
__global__ __launch_bounds__(256) void k_zdual(
    const float* __restrict__ Wo, const float* __restrict__ v1,
    float* __restrict__ z1o, u16* __restrict__ zb1o,
    const float* __restrict__ Wo2, const float* __restrict__ v2,
    float* __restrict__ z2o, u16* __restrict__ zb2o) {
  const float* W = blockIdx.z ? Wo2 : Wo;
  const float* v = blockIdx.z ? v2 : v1;
  float* z  = blockIdx.z ? z2o : z1o;
  u16* zb   = blockIdx.z ? zb2o : zb1o;
  __shared__ float As[16][68];
  __shared__ float Bs[16][64];
  const int t = threadIdx.x, tx = t & 15, ty = t >> 4;
  const int o0 = blockIdx.x * 64, bb = blockIdx.y;
  const int aoo = t >> 2, akq = (t & 3) * 4;
  const int bkk = t >> 4, bnq = (t & 15) * 4;
  float acc[4][4] = {};
  for (int k0 = 0; k0 < IN; k0 += 16) {
    {
      float4 w4 = *(const float4*)&W[(size_t)(o0 + aoo) * IN + k0 + akq];
      As[akq + 0][aoo] = w4.x; As[akq + 1][aoo] = w4.y;
      As[akq + 2][aoo] = w4.z; As[akq + 3][aoo] = w4.w;
    }
    *(float4*)&Bs[bkk][bnq] = *(const float4*)&v[((size_t)bb * IN + k0 + bkk) * ND + bnq];
    __syncthreads();
#pragma unroll
    for (int kk = 0; kk < 16; ++kk) {
      float4 a4 = *(const float4*)&As[kk][ty * 4];
      float4 b4 = *(const float4*)&Bs[kk][tx * 4];
      float ar[4] = {a4.x, a4.y, a4.z, a4.w}, br[4] = {b4.x, b4.y, b4.z, b4.w};
#pragma unroll
      for (int i = 0; i < 4; ++i)
#pragma unroll
        for (int j = 0; j < 4; ++j) acc[i][j] += ar[i] * br[j];
    }
    __syncthreads();
  }
#pragma unroll
  for (int i = 0; i < 4; ++i) {
    float4 r = make_float4(acc[i][0], acc[i][1], acc[i][2], acc[i][3]);
    const size_t off = ((size_t)bb * CH + o0 + ty * 4 + i) * ND + tx * 4;
    *(float4*)&z[off] = r;
    ushort4 h;
    h.x = f2bf(r.x); h.y = f2bf(r.y); h.z = f2bf(r.z); h.w = f2bf(r.w);
    *(ushort4*)&zb[off] = h;
  }
}

// ---------------- BN stats -------------------------------------------------
__global__ __launch_bounds__(256) void k_stats(
    const float* __restrict__ z1, const float* __restrict__ z2,
    const float* __restrict__ sp, const float* __restrict__ G,
    const float* __restrict__ gam, const float* __restrict__ bet,
    const float* __restrict__ gam2, const float* __restrict__ bet2,
    float* __restrict__ abc) {
  const int t = threadIdx.x;
  const int o = blockIdx.x * 4 + (t >> 6), lane = t & 63;
#pragma unroll
  for (int br = 0; br < 2; ++br) {
    const float* z = br ? z2 : z1;
    float macc = 0.f, eacc = 0.f;
    for (int bb = 0; bb < BB; ++bb) {
      const float zv = z[((size_t)bb * CH + o) * ND + lane];
      float s1 = zv * sp[bb * ND + lane];
      const float* Gb = G + (size_t)bb * ND * ND;
      float gz = 0.f;
      for (int k = 0; k < ND; ++k) {
        const float zk = __shfl(zv, k);
        gz += Gb[k * ND + lane] * zk;
      }
      float q = zv * gz;
#pragma unroll
      for (int off = 32; off; off >>= 1) {
        s1 += __shfl_xor(s1, off);
        q  += __shfl_xor(q, off);
      }
      macc += s1; eacc += q;
    }
    const float inv = 1.f / (float)((size_t)BB * WH);
    const float mean = macc * inv;
    const float var  = eacc * inv - mean * mean;
    const float a = (br ? gam2[o] : gam[o]) * rsqrtf(var + 1e-5f);
    const float c = (br ? bet2[o] : bet[o]) - mean * a;
    if (lane == 0) { abc[br * 2 * CH + o] = a; abc[br * 2 * CH + CH + o] = c; }
  }
}

// ---------------- epilogue: MFMA y=z.post^T, BN, residual relus ------------
__global__ __launch_bounds__(256) void k_epi(
    const u16* __restrict__ zb1, const u16* __restrict__ zb2,
    const u16* __restrict__ post, const float* __restrict__ abc,
    const float* __restrict__ x, float* __restrict__ out1, float* __restrict__ out2) {
  const int t = threadIdx.x, w = t >> 6, lr = t & 15, lg = (t >> 4) & 3;
  const int m0 = blockIdx.x * 256 + w * 64, o0 = blockIdx.y * 64, bb = blockIdx.z;
  f32x4 acc1[4][4], acc2[4][4];
#pragma unroll
  for (int i = 0; i < 4; ++i)
#pragma unroll
    for (int j = 0; j < 4; ++j) {
      acc1[i][j] = (f32x4){0.f, 0.f, 0.f, 0.f};
      acc2[i][j] = (f32x4){0.f, 0.f, 0.f, 0.f};
    }
  const u16* z1p = zb1 + ((size_t)bb * CH + o0 + lr) * ND + lg * 8;
  const u16* z2p = zb2 + ((size_t)bb * CH + o0 + lr) * ND + lg * 8;
  const u16* pp  = post + ((size_t)bb * WH + m0 + lr) * ND + lg * 8;
#pragma unroll
  for (int ks = 0; ks < 2; ++ks) {
    s16x8 a1[4], a2[4], bq[4];
#pragma unroll
    for (int i = 0; i < 4; ++i) {
      a1[i] = ld8(z1p + i * 16 * ND + ks * 32);
      a2[i] = ld8(z2p + i * 16 * ND + ks * 32);
    }
#pragma unroll
    for (int j = 0; j < 4; ++j) bq[j] = ld8(pp + j * 16 * ND + ks * 32);
#pragma unroll
    for (int i = 0; i < 4; ++i)
#pragma unroll
      for (int j = 0; j < 4; ++j) {
        acc1[i][j] = MFMA16(a1[i], bq[j], acc1[i][j]);
        acc2[i][j] = MFMA16(a2[i], bq[j], acc2[i][j]);
      }
  }
#pragma unroll
  for (int i = 0; i < 4; ++i)
#pragma unroll
    for (int r = 0; r < 4; ++r) {
      const int o = o0 + i * 16 + lg * 4 + r;
      const float a1v = abc[o], c1v = abc[CH + o];
      const float a2v = abc[2 * CH + o], c2v = abc[3 * CH + o];
      const size_t base = ((size_t)bb * CH + o) * WH + m0 + lr;
#pragma unroll
      for (int j = 0; j < 4; ++j) {
        const size_t off = base + j * 16;
        const float xv = x[off];
        out1[off] = fmaxf(fmaxf(a1v * acc1[i][j][r] + c1v, 0.f) + xv, 0.f);
        out2[off] = fmaxf(fmaxf(a2v * acc2[i][j][r] + c2v, 0.f) + xv, 0.f);
      }
    }
}

// ---------------------------------------------------------------------------
extern "C" void kernel_launch(void* const* d_in, const int* in_sizes, int n_in,
                              void* d_out, int out_size, void* d_ws, size_t ws_size,
                              hipStream_t stream) {
  (void)in_sizes; (void)n_in; (void)out_size; (void)ws_size;
  const float* x    = (const float*)d_in[0];
  const float* Win  = (const float*)d_in[1];
  const float* bin  = (const float*)d_in[2];
  const float* mp   = (const float*)d_in[3];
  const float* pi0  = (const float*)d_in[4];
  const float* Wa   = (const float*)d_in[5];
  const float* ba   = (const float*)d_in[6];
  const float* Wd   = (const float*)d_in[7];
  const float* bd   = (const float*)d_in[8];
  const float* gw   = (const float*)d_in[9];
  const float* Wo   = (const float*)d_in[10];
  const float* gam  = (const float*)d_in[12];
  const float* bet  = (const float*)d_in[13];
  const float* Wo2  = (const float*)d_in[14];
  const float* gam2 = (const float*)d_in[16];
  const float* bet2 = (const float*)d_in[17];

  char* ob = (char*)d_out;
  char* wp = (char*)d_ws;
  // scratch in d_out (dead before k_epi writes outputs):
  float* mup = (float*)(ob + 0);          // 16.8 MB (64 chunks)
  float* gp  = (float*)(ob + 16777216);   // 4.2 MB
  float* z1  = (float*)(ob + 20971520);   // 1 MB
  float* z2  = (float*)(ob + 22020096);   // 1 MB
  // ws (~21.7 MB):
  u16*   x1    = (u16*)(wp + 0);           // 8.4 MB [b][c][m]
  u16*   x1t   = (u16*)(wp + 8388608);     // 8.4 MB [b][m][c]
  u16*   Winb  = (u16*)(wp + 16777216);    // 0.5 MB
  u16*   mu_t  = (u16*)(wp + 17301504);    // 128 KB [b][n][c]
  u16*   pmn   = (u16*)(wp + 17432576);    // 2 MB [b][m][n]
  float* mu    = (float*)(wp + 19529728);  // 256 KB [b][c][n]
  float* x2g   = (float*)(wp + 19791872);  // 256 KB
  u16*   zb1   = (u16*)(wp + 20054016);    // 0.5 MB
  u16*   zb2   = (u16*)(wp + 20578304);    // 0.5 MB
  float* sp3   = (float*)(wp + 21102592);  // 3 KB
  float* piw   = (float*)(wp + 21105664);  // 1 KB
  float* abc   = (float*)(wp + 21106688);  // 16 KB
  float* G     = (float*)(wp + 21123072);  // 64 KB
  float* qbuf  = (float*)(wp + 21188608);  // 256 KB
  float* xabuf = (float*)(wp + 21450752);  // 128 KB
  float* dvb   = (float*)(wp + 21581824);  // 2 KB
  float* ahat  = (float*)(wp + 21583872);  // 64 KB
  float* out1  = (float*)d_out;
  float* out2  = out1 + TOT;

  k_init<<<dim3(1284), 256, 0, stream>>>(Win, mp, pi0, Winb, mu_t, piw, sp3);
  k_x1<<<dim3(64, BB), 512, 0, stream>>>(x, Winb, bin, x1, x1t);
  for (int it = 0; it < 3; ++it) {
    float* spb = sp3 + it * 256;
    const int doG = (it == 2);
    k_em<<<dim3(64, BB), 256, 0, stream>>>(x1, x1t, mu_t, piw, spb, pmn, mup, gp, doG);
    k_mu_red<<<dim3(256), 256, 0, stream>>>(mup, spb, piw, mu, mu_t, gp, G, doG);
  }
  k_gcA<<<dim3(7, BB), 256, 0, stream>>>(mu, gw, Wa, ba, Wd, bd, qbuf, xabuf, dvb);
  k_gcB<<<dim3(BB), 256, 0, stream>>>(xabuf, dvb, ahat);
  k_gcC<<<dim3(4, BB), 256, 0, stream>>>(qbuf, ahat, mu, x2g);
  k_zdual<<<dim3(16, BB, 2), 256, 0, stream>>>(Wo, x2g, z1, zb1, Wo2, mu, z2, zb2);
  k_stats<<<dim3(256), 256, 0, stream>>>(z1, z2, sp3 + 512, G, gam, bet, gam2, bet2, abc);
  k_epi<<<dim3(16, 16, BB), 256, 0, stream>>>(zb1, zb2, pmn, abc, x, out1, out2);
}